// Round 12
// baseline (827.220 us; speedup 1.0000x reference)
//
#include <hip/hip_runtime.h>
#include <hip/hip_bf16.h>
#include <stdint.h>

#define TOKENS 4096
#define DMODEL 1024
#define VOCAB  50257
#define KSEL   64
#define BN 128
#define BK 64
// pass A (sample): first 2048 cols, 16 splits x 128 cols, 512 blocks, BM=128
#define BMS 128
#define NSPLIT_A 16
#define COLS_A   128
#define SAMPLE_END (NSPLIT_A * COLS_A)             // 2048
#define TSZ (BMS * BK)                             // 8192 B sample tile buf
// pass B (filter): cols [2048, VOCAB), 32 splits, 512 blocks, BM=256
#define BMF 256
#define NSPLIT_B 32
#define COLS_B (VOCAB - SAMPLE_END)                // 48209
#define COLS_PER ((COLS_B + NSPLIT_B - 1) / NSPLIT_B)  // 1507
#define ATSZ (BMF * BK)                            // 16384 B A tile buf
#define BTSZ (BN * BK)                             // 8192 B B tile buf
#define SEG 128                                    // per (block,row) survivor cap
#define CAP 56
#define MERGE_THR 17
#define INF __builtin_inff()

typedef unsigned short u16;
typedef long i64;
typedef __attribute__((ext_vector_type(4))) float f32x4;

#define GLOAD16(gp, lp) __builtin_amdgcn_global_load_lds( \
    (const __attribute__((address_space(1))) void*)(gp),  \
    (__attribute__((address_space(3))) void*)(lp), 16, 0, 0)
#define GLOAD4(gp, lp) __builtin_amdgcn_global_load_lds(  \
    (const __attribute__((address_space(1))) void*)(gp),  \
    (__attribute__((address_space(3))) void*)(lp), 4, 0, 0)

// counted-vmcnt barrier: keep younger staging loads in flight (T3/T4)
#define WAITB(N) do { asm volatile("s_waitcnt vmcnt(" #N ")" ::: "memory"); \
                      __builtin_amdgcn_s_barrier(); } while (0)
// LDS-visibility-only barrier: does NOT drain vmcnt
#define LBAR() do { asm volatile("s_waitcnt lgkmcnt(0)" ::: "memory"); \
                    __builtin_amdgcn_s_barrier(); } while (0)
// drain outstanding stores (gfx9: stores count in vmcnt) without a barrier
#define DRAIN_VM() asm volatile("s_waitcnt vmcnt(0)" ::: "memory")

// ---------------------------------------------------------------------------
// Kernel 1: x,b -> fp8 e4m3 + fp32 squared norms. 1 block/row.
// ---------------------------------------------------------------------------
__global__ __launch_bounds__(256) void prep_kernel(
    const float* __restrict__ x, const float* __restrict__ b,
    uint8_t* __restrict__ xh, uint8_t* __restrict__ bh,
    float* __restrict__ xsq, float* __restrict__ bsq) {
  int row = blockIdx.x;
  int tid = threadIdx.x;
  const float* src;
  uint8_t* dst;
  float* nrm;
  int r;
  if (row < TOKENS) {
    r = row; src = x + (size_t)r * DMODEL; dst = xh + (size_t)r * DMODEL; nrm = xsq;
  } else {
    r = row - TOKENS; src = b + (size_t)r * DMODEL; dst = bh + (size_t)r * DMODEL; nrm = bsq;
  }
  float4 v = reinterpret_cast<const float4*>(src)[tid];
  float s = v.x * v.x + v.y * v.y + v.z * v.z + v.w * v.w;
  uint32_t w = __builtin_amdgcn_cvt_pk_fp8_f32(v.x, v.y, 0, false);
  w = __builtin_amdgcn_cvt_pk_fp8_f32(v.z, v.w, w, true);
  reinterpret_cast<uint32_t*>(dst)[tid] = w;
#pragma unroll
  for (int j = 1; j < 64; j <<= 1) s += __shfl_xor(s, j);
  __shared__ float acc4[4];
  if ((tid & 63) == 0) acc4[tid >> 6] = s;
  __syncthreads();
  if (tid == 0) nrm[r] = acc4[0] + acc4[1] + acc4[2] + acc4[3];
}

// ---------------------------------------------------------------------------
// merge_row: sort <=64 candidates (asc), merge 64 smallest into sorted lstv.
// ---------------------------------------------------------------------------
__device__ __attribute__((noinline)) float merge_row(float lstv, const float* cb, int cnt) {
  const int lane = threadIdx.x & 63;
  float v0 = (lane < cnt) ? cb[lane] : INF;
#pragma unroll
  for (int k = 2; k <= 64; k <<= 1) {
#pragma unroll
    for (int j = k >> 1; j > 0; j >>= 1) {
      float p = __shfl_xor(v0, j);
      bool keepmin = (((lane & j) == 0) == ((lane & k) == 0));
      v0 = keepmin ? fminf(v0, p) : fmaxf(v0, p);
    }
  }
  float rev = __shfl(v0, 63 - lane);
  float m = fminf(lstv, rev);
#pragma unroll
  for (int j = 32; j > 0; j >>= 1) {
    float p = __shfl_xor(m, j);
    m = ((lane & j) == 0) ? fminf(m, p) : fmaxf(m, p);
  }
  return m;
}

// merge64: both sorted asc across 64 lanes -> sorted asc 64 smallest of union
__device__ __forceinline__ float merge64(float a, float b, int lane) {
  float rev = __shfl(b, 63 - lane);
  float m = fminf(a, rev);
#pragma unroll
  for (int j = 32; j > 0; j >>= 1) {
    float p = __shfl_xor(m, j);
    m = ((lane & j) == 0) ? fminf(m, p) : fmaxf(m, p);
  }
  return m;
}

// ===========================================================================
// Sample-kernel GEMM machinery (fp8, 128x128 tile, BK=64) — round-10 proven
// ===========================================================================
#define STAGE_STEP(BB, KS) do {                        \
    GLOAD16(a_src + (KS), &As[(BB) + wave * 1024]);    \
    GLOAD16(b_src + (KS), &Bs[(BB) + wave * 1024]);    \
  } while (0)

#define MFMA8(a0_, a1_, b0_, b1_, b2_, b3_)                                           \
    acc[0][0] = __builtin_amdgcn_mfma_f32_16x16x32_fp8_fp8(a0_, b0_, acc[0][0], 0, 0, 0); \
    acc[0][1] = __builtin_amdgcn_mfma_f32_16x16x32_fp8_fp8(a0_, b1_, acc[0][1], 0, 0, 0); \
    acc[0][2] = __builtin_amdgcn_mfma_f32_16x16x32_fp8_fp8(a0_, b2_, acc[0][2], 0, 0, 0); \
    acc[0][3] = __builtin_amdgcn_mfma_f32_16x16x32_fp8_fp8(a0_, b3_, acc[0][3], 0, 0, 0); \
    acc[1][0] = __builtin_amdgcn_mfma_f32_16x16x32_fp8_fp8(a1_, b0_, acc[1][0], 0, 0, 0); \
    acc[1][1] = __builtin_amdgcn_mfma_f32_16x16x32_fp8_fp8(a1_, b1_, acc[1][1], 0, 0, 0); \
    acc[1][2] = __builtin_amdgcn_mfma_f32_16x16x32_fp8_fp8(a1_, b2_, acc[1][2], 0, 0, 0); \
    acc[1][3] = __builtin_amdgcn_mfma_f32_16x16x32_fp8_fp8(a1_, b3_, acc[1][3], 0, 0, 0);

#define LD8(arr, BB, off) (*reinterpret_cast<const i64*>(&(arr)[(BB) + (off)]))
#define COMPUTE_STEP(BB) do {                                                  \
    i64 a0 = LD8(As, BB, A00), a1 = LD8(As, BB, A10);                          \
    i64 b0 = LD8(Bs, BB, B00), b1 = LD8(Bs, BB, B10);                          \
    i64 b2 = LD8(Bs, BB, B20), b3 = LD8(Bs, BB, B30);                          \
    __builtin_amdgcn_s_setprio(1);                                             \
    MFMA8(a0, a1, b0, b1, b2, b3)                                              \
    __builtin_amdgcn_s_setprio(0);                                             \
    i64 a0b = LD8(As, BB, A01), a1b = LD8(As, BB, A11);                        \
    i64 b0b = LD8(Bs, BB, B01), b1b = LD8(Bs, BB, B11);                        \
    i64 b2b = LD8(Bs, BB, B21), b3b = LD8(Bs, BB, B31);                        \
    __builtin_amdgcn_s_setprio(1);                                             \
    MFMA8(a0b, a1b, b0b, b1b, b2b, b3b)                                        \
    __builtin_amdgcn_s_setprio(0);                                             \
  } while (0)

// swizzled LDS byte offset (XOR-16B, involution) — shared by both kernels
#define PO_DEF auto po = [&](int row, int c) {                                 \
    return row * 64 + ((((c >> 4) ^ ((row >> 1) & 3)) << 4) | (c & 15));       \
  };

#define GEOM_COMMON                                                            \
  const int g4 = lane >> 4, fr = lane & 15;                                    \
  const int wm = wave >> 1, wn = wave & 1;                                     \
  const int rj = g4 * 4;                                                       \
  PO_DEF                                                                       \
  const int c0 = g4 * 8, c1 = 32 + g4 * 8;                                     \
  const int rA0 = wm * 32 + fr, rA1 = rA0 + 16;                                \
  const int rB0 = wn * 64 + fr, rB1 = rB0 + 16, rB2 = rB0 + 32, rB3 = rB0 + 48;\
  const int A00 = po(rA0, c0), A01 = po(rA0, c1);                              \
  const int A10 = po(rA1, c0), A11 = po(rA1, c1);                              \
  const int B00 = po(rB0, c0), B01 = po(rB0, c1);                              \
  const int B10 = po(rB1, c0), B11 = po(rB1, c1);                              \
  const int B20 = po(rB2, c0), B21 = po(rB2, c1);                              \
  const int B30 = po(rB3, c0), B31 = po(rB3, c1);

// sample: 3-buffer pipeline (2 steps in flight)
#define K_PIPELINE3()                                                           \
    _Pragma("unroll 1")                                                         \
    for (int i = 0; i < 4; ++i) {                                               \
      const int ksb = i * 192;                                                  \
      WAITB(2); STAGE_STEP(2 * TSZ, ksb + 128); COMPUTE_STEP(0);                \
      WAITB(2); STAGE_STEP(0,       ksb + 192); COMPUTE_STEP(TSZ);              \
      WAITB(2); STAGE_STEP(TSZ,     ksb + 256); COMPUTE_STEP(2 * TSZ);          \
    }                                                                           \
    WAITB(2); STAGE_STEP(2 * TSZ, 896); COMPUTE_STEP(0);                        \
    WAITB(2); STAGE_STEP(0,       960); COMPUTE_STEP(TSZ);                      \
    WAITB(2);                           COMPUTE_STEP(2 * TSZ);                  \
    WAITB(0);                           COMPUTE_STEP(0);

// ---------------------------------------------------------------------------
// Kernel 2 (pass A): fused GEMM + exact streaming top-64 over the SAMPLE.
// 512 blocks (16 splits x 32 mtiles of 128 rows), 1 chunk each.
// ---------------------------------------------------------------------------
__global__ __launch_bounds__(512, 4) void gemm_topk_sample(
    const uint8_t* __restrict__ xh, const uint8_t* __restrict__ bh,
    const float* __restrict__ xsq, const float* __restrict__ bsqg,
    float* __restrict__ parts) {
  __shared__ uint8_t As[3 * TSZ];
  __shared__ uint8_t Bs[3 * TSZ];
  __shared__ float cbuf[BMS][CAP];
  __shared__ float tau[BMS];
  __shared__ int   ccnt[BMS];
  __shared__ float xsq_s[BMS];

  const int tid  = threadIdx.x;
  const int lane = tid & 63;
  const int wave = tid >> 6;
  const int xcd = blockIdx.x & 7, idx = blockIdx.x >> 3;
  const int mt  = xcd * 4 + (idx & 3);              // 0..31
  const int ns  = idx >> 2;                         // 0..15

  const int mrow0 = mt * BMS;
  const int col0  = ns * COLS_A;

  const int stg_row = wave * 16 + (lane >> 2);
  const int stg_gran = ((lane & 3) ^ ((lane >> 3) & 3)) << 4;
  const uint8_t* a_src = xh + (size_t)(mrow0 + stg_row) * DMODEL + stg_gran;
  const uint8_t* b_src = bh + (size_t)(col0 + stg_row) * DMODEL + stg_gran;

  if (tid < BMS) {
    xsq_s[tid] = xsq[mrow0 + tid];
    tau[tid] = INF;
    ccnt[tid] = 0;
  }
  STAGE_STEP(0, 0);
  STAGE_STEP(TSZ, BK);

  float lst[16];
#pragma unroll
  for (int i = 0; i < 16; ++i) lst[i] = INF;

  GEOM_COMMON
  const int r0 = wm * 32 + wn * 16;

  const int cbase = col0;
  f32x4 acc[2][4];
#pragma unroll
  for (int i = 0; i < 2; ++i)
#pragma unroll
    for (int j = 0; j < 4; ++j) acc[i][j] = (f32x4){0.f, 0.f, 0.f, 0.f};

  K_PIPELINE3()

#pragma unroll
  for (int p = 0; p < 4; ++p) {
    if (wn == (p & 1)) {
#pragma unroll
      for (int f2 = 0; f2 < 2; ++f2) {
        const int fn = (p >> 1) * 2 + f2;
        const int c = cbase + wn * 64 + fn * 16 + fr;
        const float bq = bsqg[c];
#pragma unroll
        for (int fm = 0; fm < 2; ++fm) {
#pragma unroll
          for (int j = 0; j < 4; ++j) {
            const int rl = wm * 32 + fm * 16 + rj + j;
            const float dist = xsq_s[rl] + bq - 2.0f * acc[fm][fn][j];
            if (dist < tau[rl]) {
              int ix = atomicAdd(&ccnt[rl], 1);
              if (ix < CAP) cbuf[rl][ix] = dist;
            }
          }
        }
      }
    }
    LBAR();
    const bool force = (p == 3);
#pragma unroll
    for (int rl16 = 0; rl16 < 16; ++rl16) {       // static idx (rule #20)
      const int r = r0 + rl16;
      const int cnt = ccnt[r];
      if (cnt >= MERGE_THR || (force && cnt > 0)) {
        float m = merge_row(lst[rl16], &cbuf[r][0], cnt);
        lst[rl16] = m;
        if (lane == 63) { tau[r] = m; ccnt[r] = 0; }
      }
    }
    LBAR();
  }

#pragma unroll
  for (int rl16 = 0; rl16 < 16; ++rl16) {
    parts[(size_t)(mrow0 + r0 + rl16) * (NSPLIT_A * KSEL) + ns * KSEL + lane] = lst[rl16];
  }
}

// ---------------------------------------------------------------------------
// Kernel 3: sample64[r][0..63] = sorted top-64 of sample (merge 16 lists).
// ---------------------------------------------------------------------------
__global__ __launch_bounds__(256) void tau_reduce_kernel(
    const float* __restrict__ parts, float* __restrict__ sample64) {
  const int lane = threadIdx.x & 63;
  const int row = blockIdx.x * 4 + (threadIdx.x >> 6);
  float v[16];
#pragma unroll
  for (int i = 0; i < 16; ++i)
    v[i] = parts[(size_t)row * (NSPLIT_A * KSEL) + i * KSEL + lane];
#pragma unroll
  for (int i = 0; i < 8; ++i) v[i] = merge64(v[i], v[i + 8], lane);
#pragma unroll
  for (int i = 0; i < 4; ++i) v[i] = merge64(v[i], v[i + 4], lane);
#pragma unroll
  for (int i = 0; i < 2; ++i) v[i] = merge64(v[i], v[i + 2], lane);
  v[0] = merge64(v[0], v[1], lane);
  sample64[(size_t)row * KSEL + lane] = v[0];
}

// ===========================================================================
// Filter-kernel GEMM machinery: 256x128 block tile, 8 waves x (64x64) each.
// 16 LDS reads -> 32 MFMA per wave per K-step (0.5 reads/MFMA).
// ===========================================================================
#define STAGE_F(N, KS) do {                                      \
    GLOAD16(a_src0 + (KS), &As[(N) * ATSZ + wave * 2048]);       \
    GLOAD16(a_src1 + (KS), &As[(N) * ATSZ + wave * 2048 + 1024]);\
    GLOAD16(b_src  + (KS), &Bs[(N) * BTSZ + wave * 1024]);       \
  } while (0)

#define MFMA16(AS, BS)                                                              \
    _Pragma("unroll")                                                               \
    for (int ms = 0; ms < 4; ++ms) {                                                \
      acc[ms][0] = __builtin_amdgcn_mfma_f32_16x16x32_fp8_fp8(AS[ms], BS[0], acc[ms][0], 0, 0, 0); \
      acc[ms][1] = __builtin_amdgcn_mfma_f32_16x16x32_fp8_fp8(AS[ms], BS[1], acc[ms][1], 0, 0, 0); \
      acc[ms][2] = __builtin_amdgcn_mfma_f32_16x16x32_fp8_fp8(AS[ms], BS[2], acc[ms][2], 0, 0, 0); \
      acc[ms][3] = __builtin_amdgcn_mfma_f32_16x16x32_fp8_fp8(AS[ms], BS[3], acc[ms][3], 0, 0, 0); \
    }

#define COMPUTE_F(N) do {                                                      \
    const int ba = (N) * ATSZ, bb = (N) * BTSZ;                                \
    i64 af[4], bf[4];                                                          \
    af[0] = LD8(As, ba, AF00); af[1] = LD8(As, ba, AF10);                      \
    af[2] = LD8(As, ba, AF20); af[3] = LD8(As, ba, AF30);                      \
    bf[0] = LD8(Bs, bb, BF00); bf[1] = LD8(Bs, bb, BF10);                      \
    bf[2] = LD8(Bs, bb, BF20); bf[3] = LD8(Bs, bb, BF30);                      \
    __builtin_amdgcn_s_setprio(1);                                             \
    MFMA16(af, bf)                                                             \
    __builtin_amdgcn_s_setprio(0);                                             \
    af[0] = LD8(As, ba, AF01); af[1] = LD8(As, ba, AF11);                      \
    af[2] = LD8(As, ba, AF21); af[3] = LD8(As, ba, AF31);                      \
    bf[0] = LD8(Bs, bb, BF01); bf[1] = LD8(Bs, bb, BF11);                      \
    bf[2] = LD8(Bs, bb, BF21); bf[3] = LD8(Bs, bb, BF31);                      \
    __builtin_amdgcn_s_setprio(1);                                             \
    MFMA16(af, bf)                                                             \
    __builtin_amdgcn_s_setprio(0);                                             \
  } while (0)

// 16-step, 3-buffer, 2-ahead, 3 loads/step -> steady WAITB(3)
#define K_PIPELINE_F()                                                          \
    _Pragma("unroll 1")                                                         \
    for (int i = 0; i < 4; ++i) {                                               \
      const int ksb = i * 192;                                                  \
      WAITB(3); STAGE_F(2, ksb + 128); COMPUTE_F(0);                            \
      WAITB(3); STAGE_F(0, ksb + 192); COMPUTE_F(1);                            \
      WAITB(3); STAGE_F(1, ksb + 256); COMPUTE_F(2);                            \
    }                                                                           \
    WAITB(3); STAGE_F(2, 896); COMPUTE_F(0);   /* t12, stage S14 */             \
    WAITB(3); STAGE_F(0, 960); COMPUTE_F(1);   /* t13, stage S15 */             \
    WAITB(3);                  COMPUTE_F(2);   /* t14 */                        \
    WAITB(0);                  COMPUTE_F(0);   /* t15 (buf0 = S15) */

// ---------------------------------------------------------------------------
// Kernel 4 (pass B): PURE fp8 GEMM, 256x128 tiles, over cols [2048, VOCAB);
// survivors (dist < tau0) -> per-(block,row) private segments, LDS counters.
// 512 blocks, 2 blocks/CU. XCD mapping: 8 mt x 8 ns per XCD so the per-XCD
// L2 footprint is A 2MB (resident) + B 1MB/chunk-period with 8-way B reuse.
// ---------------------------------------------------------------------------
__global__ __launch_bounds__(512, 4) void gemm_filter_kernel(
    const uint8_t* __restrict__ xh, const uint8_t* __restrict__ bh,
    const float* __restrict__ xsq, const float* __restrict__ bsqg,
    const float* __restrict__ sample64,
    float* __restrict__ gcand, int* __restrict__ gcnt) {
  __shared__ uint8_t As[3 * ATSZ];   // 48KB: 3 bufs of [256 rows][64 B]
  __shared__ uint8_t Bs[3 * BTSZ];   // 24KB: 3 bufs of [128 rows][64 B]
  __shared__ float bsq_s[2][BN];     // 1KB (parity by chunk)
  __shared__ float xsq_s[BMF];       // 1KB
  __shared__ float tau_s[BMF];       // 1KB
  __shared__ int   svcnt[BMF];       // 1KB
  // 76KB -> 2 blocks/CU

  const int tid  = threadIdx.x;
  const int lane = tid & 63;
  const int wave = tid >> 6;
  // L2-footprint-aware mapping: XCD x hosts mt in {(x&1)*8..+8} and
  // ns in {(x>>1)*8..+8}  (bijective: x = (ns>>3)*2 + (mt>>3))
  const int xcd = blockIdx.x & 7, idx = blockIdx.x >> 3;
  const int mt  = (xcd & 1) * 8 + (idx & 7);        // 0..15
  const int ns  = (xcd >> 1) * 8 + (idx >> 3);      // 0..31

  const int mrow0 = mt * BMF;
  const int col0  = SAMPLE_END + ns * COLS_PER;
  const int col1  = (col0 + COLS_PER < VOCAB) ? (col0 + COLS_PER) : VOCAB;
  const int nchunk = (col1 - col0 + BN - 1) / BN;

  // staging: per step each wave issues 2 A-loads (32 rows) + 1 B-load (16 rows)
  const int stg_r16 = lane >> 2;                    // row within 16-row seg
  const int stg_gran = ((lane & 3) ^ ((lane >> 3) & 3)) << 4;
  const uint8_t* a_src0 = xh + (size_t)(mrow0 + wave * 32 + stg_r16) * DMODEL + stg_gran;
  const uint8_t* a_src1 = a_src0 + (size_t)16 * DMODEL;
  int gc0 = col0 + wave * 16 + stg_r16; if (gc0 > VOCAB - 1) gc0 = VOCAB - 1;
  const uint8_t* b_src = bh + (size_t)gc0 * DMODEL + stg_gran;

#define STAGE_BSQ(CC) do {                                              \
    int c_ = col0 + (CC) * BN + lane;                                   \
    int cA_ = (c_ < VOCAB) ? c_ : (VOCAB - 1);                          \
    int cB_ = (c_ + 64 < VOCAB) ? (c_ + 64) : (VOCAB - 1);              \
    GLOAD4(bsqg + cA_, &bsq_s[(CC) & 1][0]);                            \
    GLOAD4(bsqg + cB_, &bsq_s[(CC) & 1][64]);                           \
  } while (0)

  if (tid < BMF) {                    // plain loads BEFORE counted staging
    xsq_s[tid] = xsq[mrow0 + tid];
    tau_s[tid] = sample64[(size_t)(mrow0 + tid) * KSEL + (KSEL - 1)];
    svcnt[tid] = 0;
  }
  // chunk-0 prologue: bsq(2) + S0(3) + S1(3) outstanding
  STAGE_BSQ(0);
  STAGE_F(0, 0);
  STAGE_F(1, BK);

  // fragment geometry: wave tile 64x64 at (wm*64, wn*64); 4 m-strips, 4 n-strips
  const int g4 = lane >> 4, fr = lane & 15;
  const int wm = wave >> 1, wn = wave & 1;          // wm 0..3, wn 0..1
  const int rj = g4 * 4;
  PO_DEF
  const int c0 = g4 * 8, c1 = 32 + g4 * 8;
  const int AF00 = po(wm * 64 +  0 + fr, c0), AF01 = po(wm * 64 +  0 + fr, c1);
  const int AF10 = po(wm * 64 + 16 + fr, c0), AF11 = po(wm * 64 + 16 + fr, c1);
  const int AF20 = po(wm * 64 + 32 + fr, c0), AF21 = po(wm * 64 + 32 + fr, c1);
  const int AF30 = po(wm * 64 + 48 + fr, c0), AF31 = po(wm * 64 + 48 + fr, c1);
  const int BF00 = po(wn * 64 +  0 + fr, c0), BF01 = po(wn * 64 +  0 + fr, c1);
  const int BF10 = po(wn * 64 + 16 + fr, c0), BF11 = po(wn * 64 + 16 + fr, c1);
  const int BF20 = po(wn * 64 + 32 + fr, c0), BF21 = po(wn * 64 + 32 + fr, c1);
  const int BF30 = po(wn * 64 + 48 + fr, c0), BF31 = po(wn * 64 + 48 + fr, c1);

  float* seg_base = gcand + (size_t)mrow0 * (NSPLIT_B * SEG) + (size_t)ns * SEG;

#pragma unroll 1
  for (int ch = 0; ch < nchunk; ++ch) {
    const int cbase = col0 + ch * BN;
    f32x4 acc[4][4];                  // 64 VGPR accumulator (64x64 outputs)
#pragma unroll
    for (int i = 0; i < 4; ++i)
#pragma unroll
      for (int j = 0; j < 4; ++j) acc[i][j] = (f32x4){0.f, 0.f, 0.f, 0.f};

    K_PIPELINE_F()
    // WAITB(0) drained; barrier passed -> tiles + bsq_s readable.

    // ---- filter epilogue: dist < tau0 -> LDS-counted private segment ----
#pragma unroll
    for (int nf = 0; nf < 4; ++nf) {
      const int c = cbase + wn * 64 + nf * 16 + fr;
      const bool cv = (c < col1);
      const float bq = bsq_s[ch & 1][wn * 64 + nf * 16 + fr];
#pragma unroll
      for (int ms = 0; ms < 4; ++ms) {
#pragma unroll
        for (int j = 0; j < 4; ++j) {
          const int rl = wm * 64 + ms * 16 + rj + j;
          const float dist = xsq_s[rl] + bq - 2.0f * acc[ms][nf][j];
          if (cv && dist < tau_s[rl]) {
            int ix = atomicAdd(&svcnt[rl], 1);       // LDS atomic (rare: ~3%)
            if (ix < SEG)
              seg_base[(size_t)rl * (NSPLIT_B * SEG) + ix] = dist;
          }
        }
      }
    }
    DRAIN_VM();                       // retire stores: vmcnt ledger stays clean
    LBAR();                           // all waves past t15 compute (buf0 WAR)
    if (ch + 1 < nchunk) {            // next-chunk prologue under epilogue tail
      STAGE_BSQ(ch + 1);
      int gcn = col0 + (ch + 1) * BN + wave * 16 + stg_r16;
      if (gcn > VOCAB - 1) gcn = VOCAB - 1;
      b_src = bh + (size_t)gcn * DMODEL + stg_gran;
      STAGE_F(0, 0);
      STAGE_F(1, BK);
    }
  }

  LBAR();                             // all LDS atomics visible
  if (tid < BMF) {
    int c = svcnt[tid]; if (c > SEG) c = SEG;
    gcnt[(size_t)(mrow0 + tid) * NSPLIT_B + ns] = c;
  }
}

// ---------------------------------------------------------------------------
// Kernel 5 (pass C): per row, top-64 = sample64 merged with all survivors
// from the 32 per-block segments. One wave per row.
// ---------------------------------------------------------------------------
__global__ __launch_bounds__(256) void select_kernel(
    const float* __restrict__ gcand, const int* __restrict__ gcnt,
    const float* __restrict__ sample64, float* __restrict__ out) {
  const int lane = threadIdx.x & 63;
  const int row = blockIdx.x * 4 + (threadIdx.x >> 6);
  float lst = sample64[(size_t)row * KSEL + lane];   // sorted asc
#pragma unroll 1
  for (int s = 0; s < NSPLIT_B; ++s) {
    int cnt = gcnt[(size_t)row * NSPLIT_B + s];
    const float* src = gcand + (size_t)row * (NSPLIT_B * SEG) + (size_t)s * SEG;
#pragma unroll 1
    for (int base = 0; base < cnt; base += 64) {
      int n = cnt - base; if (n > 64) n = 64;
      lst = merge_row(lst, src + base, n);
    }
  }
  out[(size_t)row * KSEL + lane] = lst;
}

// ---------------------------------------------------------------------------
extern "C" void kernel_launch(void* const* d_in, const int* in_sizes, int n_in,
                              void* d_out, int out_size, void* d_ws, size_t ws_size,
                              hipStream_t stream) {
  const float* x = (const float*)d_in[0];
  const float* b = (const float*)d_in[1];
  // d_in[2] = target (unused), d_in[3] = k (hardcoded 64)
  float* out = (float*)d_out;
  char* ws = (char*)d_ws;

  size_t off = 0;
  uint8_t* xh = (uint8_t*)(ws + off); off += (size_t)TOKENS * DMODEL;          // 4.2 MB
  uint8_t* bh = (uint8_t*)(ws + off); off += (size_t)VOCAB * DMODEL;           // 51.5 MB
  off = (off + 255) & ~(size_t)255;
  float* xsq = (float*)(ws + off); off += (size_t)TOKENS * sizeof(float);
  float* bsq = (float*)(ws + off); off += (((size_t)VOCAB * sizeof(float)) + 255) & ~(size_t)255;
  float* sample64 = (float*)(ws + off); off += (size_t)TOKENS * KSEL * sizeof(float);         // 1 MB
  int* gcnt = (int*)(ws + off); off += (size_t)TOKENS * NSPLIT_B * sizeof(int);               // 512 KB
  float* parts = (float*)(ws + off); off += (size_t)TOKENS * NSPLIT_A * KSEL * sizeof(float); // 16.8 MB
  float* gcand = (float*)(ws + off); off += (size_t)TOKENS * NSPLIT_B * SEG * sizeof(float);  // 67 MB

  prep_kernel<<<TOKENS + VOCAB, 256, 0, stream>>>(x, b, xh, bh, xsq, bsq);
  gemm_topk_sample<<<(TOKENS / BMS) * NSPLIT_A, 512, 0, stream>>>(xh, bh, xsq, bsq, parts);
  tau_reduce_kernel<<<TOKENS / 4, 256, 0, stream>>>(parts, sample64);
  gemm_filter_kernel<<<(TOKENS / BMF) * NSPLIT_B, 512, 0, stream>>>(xh, bh, xsq, bsq, sample64, gcand, gcnt);
  select_kernel<<<TOKENS / 4, 256, 0, stream>>>(gcand, gcnt, sample64, out);
}

// Round 13
// 723.487 us; speedup vs baseline: 1.1434x; 1.1434x over previous
//
#include <hip/hip_runtime.h>
#include <hip/hip_bf16.h>
#include <stdint.h>

#define TOKENS 4096
#define DMODEL 1024
#define VOCAB  50257
#define KSEL   64
#define BK 64
// pass A (sample): first 2048 cols, 16 splits x 128 cols, 512 blocks, BM=128
#define BMS 128
#define NSPLIT_A 16
#define COLS_A   128
#define SAMPLE_END (NSPLIT_A * COLS_A)             // 2048
#define TSZ (BMS * BK)                             // 8192 B sample tile buf
// pass B (filter): cols [2048, VOCAB), 16 splits, 512 blocks, BM=128, BN=256
#define BMF 128
#define BNF 256
#define NSPLIT_B 16
#define COLS_B (VOCAB - SAMPLE_END)                // 48209
#define COLS_PER ((COLS_B + NSPLIT_B - 1) / NSPLIT_B)  // 3014
#define ATSZ (BMF * BK)                            // 8192 B A tile buf
#define BTSZ (BNF * BK)                            // 16384 B B tile buf
#define SEG 256                                    // per (block,row) survivor cap
#define CAP 56
#define MERGE_THR 17
#define INF __builtin_inff()

typedef unsigned short u16;
typedef long i64;
typedef __attribute__((ext_vector_type(4))) float f32x4;

#define GLOAD16(gp, lp) __builtin_amdgcn_global_load_lds( \
    (const __attribute__((address_space(1))) void*)(gp),  \
    (__attribute__((address_space(3))) void*)(lp), 16, 0, 0)
#define GLOAD4(gp, lp) __builtin_amdgcn_global_load_lds(  \
    (const __attribute__((address_space(1))) void*)(gp),  \
    (__attribute__((address_space(3))) void*)(lp), 4, 0, 0)

// counted-vmcnt barrier: keep younger staging loads in flight (T3/T4)
#define WAITB(N) do { asm volatile("s_waitcnt vmcnt(" #N ")" ::: "memory"); \
                      __builtin_amdgcn_s_barrier(); } while (0)
// LDS-visibility-only barrier: does NOT drain vmcnt
#define LBAR() do { asm volatile("s_waitcnt lgkmcnt(0)" ::: "memory"); \
                    __builtin_amdgcn_s_barrier(); } while (0)
// drain outstanding stores (gfx9: stores count in vmcnt) without a barrier
#define DRAIN_VM() asm volatile("s_waitcnt vmcnt(0)" ::: "memory")

// ---------------------------------------------------------------------------
// Kernel 1: x,b -> fp8 e4m3 + fp32 squared norms. 1 block/row.
// ---------------------------------------------------------------------------
__global__ __launch_bounds__(256) void prep_kernel(
    const float* __restrict__ x, const float* __restrict__ b,
    uint8_t* __restrict__ xh, uint8_t* __restrict__ bh,
    float* __restrict__ xsq, float* __restrict__ bsq) {
  int row = blockIdx.x;
  int tid = threadIdx.x;
  const float* src;
  uint8_t* dst;
  float* nrm;
  int r;
  if (row < TOKENS) {
    r = row; src = x + (size_t)r * DMODEL; dst = xh + (size_t)r * DMODEL; nrm = xsq;
  } else {
    r = row - TOKENS; src = b + (size_t)r * DMODEL; dst = bh + (size_t)r * DMODEL; nrm = bsq;
  }
  float4 v = reinterpret_cast<const float4*>(src)[tid];
  float s = v.x * v.x + v.y * v.y + v.z * v.z + v.w * v.w;
  uint32_t w = __builtin_amdgcn_cvt_pk_fp8_f32(v.x, v.y, 0, false);
  w = __builtin_amdgcn_cvt_pk_fp8_f32(v.z, v.w, w, true);
  reinterpret_cast<uint32_t*>(dst)[tid] = w;
#pragma unroll
  for (int j = 1; j < 64; j <<= 1) s += __shfl_xor(s, j);
  __shared__ float acc4[4];
  if ((tid & 63) == 0) acc4[tid >> 6] = s;
  __syncthreads();
  if (tid == 0) nrm[r] = acc4[0] + acc4[1] + acc4[2] + acc4[3];
}

// ---------------------------------------------------------------------------
// merge_row: sort <=64 candidates (asc), merge 64 smallest into sorted lstv.
// ---------------------------------------------------------------------------
__device__ __attribute__((noinline)) float merge_row(float lstv, const float* cb, int cnt) {
  const int lane = threadIdx.x & 63;
  float v0 = (lane < cnt) ? cb[lane] : INF;
#pragma unroll
  for (int k = 2; k <= 64; k <<= 1) {
#pragma unroll
    for (int j = k >> 1; j > 0; j >>= 1) {
      float p = __shfl_xor(v0, j);
      bool keepmin = (((lane & j) == 0) == ((lane & k) == 0));
      v0 = keepmin ? fminf(v0, p) : fmaxf(v0, p);
    }
  }
  float rev = __shfl(v0, 63 - lane);
  float m = fminf(lstv, rev);
#pragma unroll
  for (int j = 32; j > 0; j >>= 1) {
    float p = __shfl_xor(m, j);
    m = ((lane & j) == 0) ? fminf(m, p) : fmaxf(m, p);
  }
  return m;
}

// merge64: both sorted asc across 64 lanes -> sorted asc 64 smallest of union
__device__ __forceinline__ float merge64(float a, float b, int lane) {
  float rev = __shfl(b, 63 - lane);
  float m = fminf(a, rev);
#pragma unroll
  for (int j = 32; j > 0; j >>= 1) {
    float p = __shfl_xor(m, j);
    m = ((lane & j) == 0) ? fminf(m, p) : fmaxf(m, p);
  }
  return m;
}

// ===========================================================================
// Sample-kernel GEMM machinery (fp8, 128x128 tile, BK=64) — round-10 proven
// ===========================================================================
#define STAGE_STEP(BB, KS) do {                        \
    GLOAD16(a_src + (KS), &As[(BB) + wave * 1024]);    \
    GLOAD16(b_src + (KS), &Bs[(BB) + wave * 1024]);    \
  } while (0)

#define MFMA8(a0_, a1_, b0_, b1_, b2_, b3_)                                           \
    acc[0][0] = __builtin_amdgcn_mfma_f32_16x16x32_fp8_fp8(a0_, b0_, acc[0][0], 0, 0, 0); \
    acc[0][1] = __builtin_amdgcn_mfma_f32_16x16x32_fp8_fp8(a0_, b1_, acc[0][1], 0, 0, 0); \
    acc[0][2] = __builtin_amdgcn_mfma_f32_16x16x32_fp8_fp8(a0_, b2_, acc[0][2], 0, 0, 0); \
    acc[0][3] = __builtin_amdgcn_mfma_f32_16x16x32_fp8_fp8(a0_, b3_, acc[0][3], 0, 0, 0); \
    acc[1][0] = __builtin_amdgcn_mfma_f32_16x16x32_fp8_fp8(a1_, b0_, acc[1][0], 0, 0, 0); \
    acc[1][1] = __builtin_amdgcn_mfma_f32_16x16x32_fp8_fp8(a1_, b1_, acc[1][1], 0, 0, 0); \
    acc[1][2] = __builtin_amdgcn_mfma_f32_16x16x32_fp8_fp8(a1_, b2_, acc[1][2], 0, 0, 0); \
    acc[1][3] = __builtin_amdgcn_mfma_f32_16x16x32_fp8_fp8(a1_, b3_, acc[1][3], 0, 0, 0);

#define LD8(arr, BB, off) (*reinterpret_cast<const i64*>(&(arr)[(BB) + (off)]))
#define COMPUTE_STEP(BB) do {                                                  \
    i64 a0 = LD8(As, BB, A00), a1 = LD8(As, BB, A10);                          \
    i64 b0 = LD8(Bs, BB, B00), b1 = LD8(Bs, BB, B10);                          \
    i64 b2 = LD8(Bs, BB, B20), b3 = LD8(Bs, BB, B30);                          \
    __builtin_amdgcn_s_setprio(1);                                             \
    MFMA8(a0, a1, b0, b1, b2, b3)                                              \
    __builtin_amdgcn_s_setprio(0);                                             \
    i64 a0b = LD8(As, BB, A01), a1b = LD8(As, BB, A11);                        \
    i64 b0b = LD8(Bs, BB, B01), b1b = LD8(Bs, BB, B11);                        \
    i64 b2b = LD8(Bs, BB, B21), b3b = LD8(Bs, BB, B31);                        \
    __builtin_amdgcn_s_setprio(1);                                             \
    MFMA8(a0b, a1b, b0b, b1b, b2b, b3b)                                        \
    __builtin_amdgcn_s_setprio(0);                                             \
  } while (0)

// swizzled LDS byte offset (XOR-16B, involution) — shared by both kernels
#define PO_DEF auto po = [&](int row, int c) {                                 \
    return row * 64 + ((((c >> 4) ^ ((row >> 1) & 3)) << 4) | (c & 15));       \
  };

#define GEOM_COMMON                                                            \
  const int g4 = lane >> 4, fr = lane & 15;                                    \
  const int wm = wave >> 1, wn = wave & 1;                                     \
  const int rj = g4 * 4;                                                       \
  PO_DEF                                                                       \
  const int c0 = g4 * 8, c1 = 32 + g4 * 8;                                     \
  const int rA0 = wm * 32 + fr, rA1 = rA0 + 16;                                \
  const int rB0 = wn * 64 + fr, rB1 = rB0 + 16, rB2 = rB0 + 32, rB3 = rB0 + 48;\
  const int A00 = po(rA0, c0), A01 = po(rA0, c1);                              \
  const int A10 = po(rA1, c0), A11 = po(rA1, c1);                              \
  const int B00 = po(rB0, c0), B01 = po(rB0, c1);                              \
  const int B10 = po(rB1, c0), B11 = po(rB1, c1);                              \
  const int B20 = po(rB2, c0), B21 = po(rB2, c1);                              \
  const int B30 = po(rB3, c0), B31 = po(rB3, c1);

// sample: 3-buffer pipeline (2 steps in flight)
#define K_PIPELINE3()                                                           \
    _Pragma("unroll 1")                                                         \
    for (int i = 0; i < 4; ++i) {                                               \
      const int ksb = i * 192;                                                  \
      WAITB(2); STAGE_STEP(2 * TSZ, ksb + 128); COMPUTE_STEP(0);                \
      WAITB(2); STAGE_STEP(0,       ksb + 192); COMPUTE_STEP(TSZ);              \
      WAITB(2); STAGE_STEP(TSZ,     ksb + 256); COMPUTE_STEP(2 * TSZ);          \
    }                                                                           \
    WAITB(2); STAGE_STEP(2 * TSZ, 896); COMPUTE_STEP(0);                        \
    WAITB(2); STAGE_STEP(0,       960); COMPUTE_STEP(TSZ);                      \
    WAITB(2);                           COMPUTE_STEP(2 * TSZ);                  \
    WAITB(0);                           COMPUTE_STEP(0);

// ---------------------------------------------------------------------------
// Kernel 2 (pass A): fused GEMM + exact streaming top-64 over the SAMPLE.
// 512 blocks (16 splits x 32 mtiles of 128 rows), 1 chunk each.
// ---------------------------------------------------------------------------
__global__ __launch_bounds__(512, 4) void gemm_topk_sample(
    const uint8_t* __restrict__ xh, const uint8_t* __restrict__ bh,
    const float* __restrict__ xsq, const float* __restrict__ bsqg,
    float* __restrict__ parts) {
  __shared__ uint8_t As[3 * TSZ];
  __shared__ uint8_t Bs[3 * TSZ];
  __shared__ float cbuf[BMS][CAP];
  __shared__ float tau[BMS];
  __shared__ int   ccnt[BMS];
  __shared__ float xsq_s[BMS];

  const int tid  = threadIdx.x;
  const int lane = tid & 63;
  const int wave = tid >> 6;
  const int xcd = blockIdx.x & 7, idx = blockIdx.x >> 3;
  const int mt  = xcd * 4 + (idx & 3);              // 0..31
  const int ns  = idx >> 2;                         // 0..15

  const int mrow0 = mt * BMS;
  const int col0  = ns * COLS_A;

  const int stg_row = wave * 16 + (lane >> 2);
  const int stg_gran = ((lane & 3) ^ ((lane >> 3) & 3)) << 4;
  const uint8_t* a_src = xh + (size_t)(mrow0 + stg_row) * DMODEL + stg_gran;
  const uint8_t* b_src = bh + (size_t)(col0 + stg_row) * DMODEL + stg_gran;

  if (tid < BMS) {
    xsq_s[tid] = xsq[mrow0 + tid];
    tau[tid] = INF;
    ccnt[tid] = 0;
  }
  STAGE_STEP(0, 0);
  STAGE_STEP(TSZ, BK);

  float lst[16];
#pragma unroll
  for (int i = 0; i < 16; ++i) lst[i] = INF;

  GEOM_COMMON
  const int r0 = wm * 32 + wn * 16;

  const int cbase = col0;
  f32x4 acc[2][4];
#pragma unroll
  for (int i = 0; i < 2; ++i)
#pragma unroll
    for (int j = 0; j < 4; ++j) acc[i][j] = (f32x4){0.f, 0.f, 0.f, 0.f};

  K_PIPELINE3()

#pragma unroll
  for (int p = 0; p < 4; ++p) {
    if (wn == (p & 1)) {
#pragma unroll
      for (int f2 = 0; f2 < 2; ++f2) {
        const int fn = (p >> 1) * 2 + f2;
        const int c = cbase + wn * 64 + fn * 16 + fr;
        const float bq = bsqg[c];
#pragma unroll
        for (int fm = 0; fm < 2; ++fm) {
#pragma unroll
          for (int j = 0; j < 4; ++j) {
            const int rl = wm * 32 + fm * 16 + rj + j;
            const float dist = xsq_s[rl] + bq - 2.0f * acc[fm][fn][j];
            if (dist < tau[rl]) {
              int ix = atomicAdd(&ccnt[rl], 1);
              if (ix < CAP) cbuf[rl][ix] = dist;
            }
          }
        }
      }
    }
    LBAR();
    const bool force = (p == 3);
#pragma unroll
    for (int rl16 = 0; rl16 < 16; ++rl16) {       // static idx (rule #20)
      const int r = r0 + rl16;
      const int cnt = ccnt[r];
      if (cnt >= MERGE_THR || (force && cnt > 0)) {
        float m = merge_row(lst[rl16], &cbuf[r][0], cnt);
        lst[rl16] = m;
        if (lane == 63) { tau[r] = m; ccnt[r] = 0; }
      }
    }
    LBAR();
  }

#pragma unroll
  for (int rl16 = 0; rl16 < 16; ++rl16) {
    parts[(size_t)(mrow0 + r0 + rl16) * (NSPLIT_A * KSEL) + ns * KSEL + lane] = lst[rl16];
  }
}

// ---------------------------------------------------------------------------
// Kernel 3: sample64[r][0..63] = sorted top-64 of sample (merge 16 lists).
// ---------------------------------------------------------------------------
__global__ __launch_bounds__(256) void tau_reduce_kernel(
    const float* __restrict__ parts, float* __restrict__ sample64) {
  const int lane = threadIdx.x & 63;
  const int row = blockIdx.x * 4 + (threadIdx.x >> 6);
  float v[16];
#pragma unroll
  for (int i = 0; i < 16; ++i)
    v[i] = parts[(size_t)row * (NSPLIT_A * KSEL) + i * KSEL + lane];
#pragma unroll
  for (int i = 0; i < 8; ++i) v[i] = merge64(v[i], v[i + 8], lane);
#pragma unroll
  for (int i = 0; i < 4; ++i) v[i] = merge64(v[i], v[i + 4], lane);
#pragma unroll
  for (int i = 0; i < 2; ++i) v[i] = merge64(v[i], v[i + 2], lane);
  v[0] = merge64(v[0], v[1], lane);
  sample64[(size_t)row * KSEL + lane] = v[0];
}

// ===========================================================================
// Filter-kernel GEMM machinery: 128x256 block tile, 8 waves x (32x128) each.
// Per K-step per wave: 20 ds_read_b64 feed 32 MFMA (0.625 reads/MFMA, vs
// round-10's 0.75) AND block-steps halve; A-panel re-reads halve (12 chunks).
// ===========================================================================
#define STAGE_FB(N, KS) do {                                     \
    GLOAD16(a_src  + (KS), &As[(N) * ATSZ + wave * 1024]);       \
    GLOAD16(b_src0 + (KS), &Bs[(N) * BTSZ + wave * 2048]);       \
    GLOAD16(b_src1 + (KS), &Bs[(N) * BTSZ + wave * 2048 + 1024]);\
  } while (0)

#define MFMA_ROWPAIR(a0_, a1_, b_, NF)                                               \
    acc[0][NF] = __builtin_amdgcn_mfma_f32_16x16x32_fp8_fp8(a0_, b_, acc[0][NF], 0, 0, 0); \
    acc[1][NF] = __builtin_amdgcn_mfma_f32_16x16x32_fp8_fp8(a1_, b_, acc[1][NF], 0, 0, 0);

#define COMPUTE_HALF(ba, bb, AOFF, BOFF) do {                                  \
    i64 a0 = LD8(As, ba, AOFF), a1 = LD8(As, ba, (AOFF) + 1024);               \
    i64 b0 = LD8(Bs, bb, BOFF),        b1 = LD8(Bs, bb, (BOFF) + 1024);        \
    i64 b2 = LD8(Bs, bb, (BOFF) + 2048), b3 = LD8(Bs, bb, (BOFF) + 3072);      \
    i64 b4 = LD8(Bs, bb, (BOFF) + 4096), b5 = LD8(Bs, bb, (BOFF) + 5120);      \
    i64 b6 = LD8(Bs, bb, (BOFF) + 6144), b7 = LD8(Bs, bb, (BOFF) + 7168);      \
    __builtin_amdgcn_s_setprio(1);                                             \
    MFMA_ROWPAIR(a0, a1, b0, 0) MFMA_ROWPAIR(a0, a1, b1, 1)                    \
    MFMA_ROWPAIR(a0, a1, b2, 2) MFMA_ROWPAIR(a0, a1, b3, 3)                    \
    MFMA_ROWPAIR(a0, a1, b4, 4) MFMA_ROWPAIR(a0, a1, b5, 5)                    \
    MFMA_ROWPAIR(a0, a1, b6, 6) MFMA_ROWPAIR(a0, a1, b7, 7)                    \
    __builtin_amdgcn_s_setprio(0);                                             \
  } while (0)

#define COMPUTE_FX(N) do {                                                     \
    const int ba = (N) * ATSZ, bb = (N) * BTSZ;                                \
    COMPUTE_HALF(ba, bb, AF0, BF0);                                            \
    COMPUTE_HALF(ba, bb, AF1, BF1);                                            \
  } while (0)

// 16-step, 3-buffer, 2-ahead, 3 loads/step -> steady WAITB(3)
#define K_PIPELINE_FB()                                                         \
    _Pragma("unroll 1")                                                         \
    for (int i = 0; i < 4; ++i) {                                               \
      const int ksb = i * 192;                                                  \
      WAITB(3); STAGE_FB(2, ksb + 128); COMPUTE_FX(0);                          \
      WAITB(3); STAGE_FB(0, ksb + 192); COMPUTE_FX(1);                          \
      WAITB(3); STAGE_FB(1, ksb + 256); COMPUTE_FX(2);                          \
    }                                                                           \
    WAITB(3); STAGE_FB(2, 896); COMPUTE_FX(0);   /* t12, stage S14->buf2 */     \
    WAITB(3); STAGE_FB(0, 960); COMPUTE_FX(1);   /* t13, stage S15->buf0 */     \
    WAITB(3);                   COMPUTE_FX(2);   /* t14 (S14 resident) */       \
    WAITB(0);                   COMPUTE_FX(0);   /* t15 (buf0 = S15) */

// ---------------------------------------------------------------------------
// Kernel 4 (pass B): PURE fp8 GEMM, 128x256 tiles, over cols [2048, VOCAB);
// survivors (dist < tau0) -> per-(block,row) private segments, LDS counters.
// 512 blocks, SAME grid/XCD-mapping/ledger discipline as round 10.
// LDS 75.5KB -> 2 blocks/CU.
// ---------------------------------------------------------------------------
__global__ __launch_bounds__(512, 4) void gemm_filter_kernel(
    const uint8_t* __restrict__ xh, const uint8_t* __restrict__ bh,
    const float* __restrict__ xsq, const float* __restrict__ bsqg,
    const float* __restrict__ sample64,
    float* __restrict__ gcand, int* __restrict__ gcnt) {
  __shared__ uint8_t As[3 * ATSZ];   // 24KB: 3 bufs of [128 rows][64 B]
  __shared__ uint8_t Bs[3 * BTSZ];   // 48KB: 3 bufs of [256 rows][64 B]
  __shared__ float bsq_s[2][BNF];    // 2KB (parity by chunk)
  __shared__ float xsq_s[BMF];       // 512B
  __shared__ float tau_s[BMF];       // 512B
  __shared__ int   svcnt[BMF];       // 512B
  // ~75.5KB -> 2 blocks/CU

  const int tid  = threadIdx.x;
  const int lane = tid & 63;
  const int wave = tid >> 6;
  // round-10 proven mapping: each XCD owns 4 contiguous mtiles, all ns
  const int xcd = blockIdx.x & 7, idx = blockIdx.x >> 3;
  const int mt  = xcd * 4 + (idx & 3);              // 0..31
  const int ns  = idx >> 2;                         // 0..15

  const int mrow0 = mt * BMF;
  const int col0  = SAMPLE_END + ns * COLS_PER;
  const int col1  = (col0 + COLS_PER < VOCAB) ? (col0 + COLS_PER) : VOCAB;
  const int nchunk = (col1 - col0 + BNF - 1) / BNF;      // 12

  // staging: per step each wave: 1 A-load (16 rows) + 2 B-loads (32 rows)
  const int stg_r16 = lane >> 2;                    // row within 16-row seg
  const int stg_gran = ((lane & 3) ^ ((lane >> 3) & 3)) << 4;
  const uint8_t* a_src = xh + (size_t)(mrow0 + wave * 16 + stg_r16) * DMODEL + stg_gran;
  int gb0 = col0 + wave * 32 + stg_r16; if (gb0 > VOCAB - 1) gb0 = VOCAB - 1;
  int gb1 = col0 + wave * 32 + 16 + stg_r16; if (gb1 > VOCAB - 1) gb1 = VOCAB - 1;
  const uint8_t* b_src0 = bh + (size_t)gb0 * DMODEL + stg_gran;
  const uint8_t* b_src1 = bh + (size_t)gb1 * DMODEL + stg_gran;

#define STAGE_BSQ(CC) do {                                              \
    int c_ = col0 + (CC) * BNF + lane;                                  \
    _Pragma("unroll")                                                   \
    for (int q = 0; q < 4; ++q) {                                       \
      int cq = c_ + q * 64; if (cq > VOCAB - 1) cq = VOCAB - 1;         \
      GLOAD4(bsqg + cq, &bsq_s[(CC) & 1][q * 64]);                      \
    }                                                                   \
  } while (0)

  if (tid < BMF) {                    // plain loads BEFORE counted staging
    xsq_s[tid] = xsq[mrow0 + tid];
    tau_s[tid] = sample64[(size_t)(mrow0 + tid) * KSEL + (KSEL - 1)];
    svcnt[tid] = 0;
  }
  // chunk-0 prologue: bsq(4) + S0(3) + S1(3) = 10 outstanding
  STAGE_BSQ(0);
  STAGE_FB(0, 0);
  STAGE_FB(1, BK);

  // fragment geometry: wave tile 32(M) x 128(N) at (wm*32, wn*128).
  // po(row+16k, c) = po(row, c) + 1024k  (XOR term invariant: 16 ≡ 0 mod 8)
  const int g4 = lane >> 4, fr = lane & 15;
  const int wm = wave >> 1, wn = wave & 1;          // wm 0..3, wn 0..1
  const int rj = g4 * 4;
  PO_DEF
  const int c0 = g4 * 8, c1 = 32 + g4 * 8;
  const int AF0 = po(wm * 32 + fr, c0), AF1 = po(wm * 32 + fr, c1);
  const int BF0 = po(wn * 128 + fr, c0), BF1 = po(wn * 128 + fr, c1);

  float* seg_base = gcand + (size_t)mrow0 * (NSPLIT_B * SEG) + (size_t)ns * SEG;

#pragma unroll 1
  for (int ch = 0; ch < nchunk; ++ch) {
    const int cbase = col0 + ch * BNF;
    f32x4 acc[2][8];                  // 64 VGPR accumulator (32x128 outputs)
#pragma unroll
    for (int i = 0; i < 2; ++i)
#pragma unroll
      for (int j = 0; j < 8; ++j) acc[i][j] = (f32x4){0.f, 0.f, 0.f, 0.f};

    K_PIPELINE_FB()
    // WAITB(0) drained; barrier passed -> tiles + bsq_s readable.

    // ---- filter epilogue: dist < tau0 -> LDS-counted private segment ----
#pragma unroll
    for (int nf = 0; nf < 8; ++nf) {
      const int c = cbase + wn * 128 + nf * 16 + fr;
      const bool cv = (c < col1);
      const float bq = bsq_s[ch & 1][wn * 128 + nf * 16 + fr];
#pragma unroll
      for (int fm = 0; fm < 2; ++fm) {
#pragma unroll
        for (int j = 0; j < 4; ++j) {
          const int rl = wm * 32 + fm * 16 + rj + j;
          const float dist = xsq_s[rl] + bq - 2.0f * acc[fm][nf][j];
          if (cv && dist < tau_s[rl]) {
            int ix = atomicAdd(&svcnt[rl], 1);       // LDS atomic (rare: ~3%)
            if (ix < SEG)
              seg_base[(size_t)rl * (NSPLIT_B * SEG) + ix] = dist;
          }
        }
      }
    }
    DRAIN_VM();                       // retire stores: vmcnt ledger stays clean
    LBAR();                           // all waves past t15 (buf0 WAR-safe)
    if (ch + 1 < nchunk) {            // next-chunk prologue under epilogue tail
      STAGE_BSQ(ch + 1);
      int gn0 = col0 + (ch + 1) * BNF + wave * 32 + stg_r16;
      if (gn0 > VOCAB - 1) gn0 = VOCAB - 1;
      int gn1 = col0 + (ch + 1) * BNF + wave * 32 + 16 + stg_r16;
      if (gn1 > VOCAB - 1) gn1 = VOCAB - 1;
      b_src0 = bh + (size_t)gn0 * DMODEL + stg_gran;
      b_src1 = bh + (size_t)gn1 * DMODEL + stg_gran;
      STAGE_FB(0, 0);
      STAGE_FB(1, BK);
    }
  }

  LBAR();                             // all LDS atomics visible
  if (tid < BMF) {
    int c = svcnt[tid]; if (c > SEG) c = SEG;
    gcnt[(size_t)(mrow0 + tid) * NSPLIT_B + ns] = c;
  }
}

// ---------------------------------------------------------------------------
// Kernel 5 (pass C): per row, top-64 = sample64 merged with all survivors
// from the 16 per-block segments. One wave per row.
// ---------------------------------------------------------------------------
__global__ __launch_bounds__(256) void select_kernel(
    const float* __restrict__ gcand, const int* __restrict__ gcnt,
    const float* __restrict__ sample64, float* __restrict__ out) {
  const int lane = threadIdx.x & 63;
  const int row = blockIdx.x * 4 + (threadIdx.x >> 6);
  float lst = sample64[(size_t)row * KSEL + lane];   // sorted asc
#pragma unroll 1
  for (int s = 0; s < NSPLIT_B; ++s) {
    int cnt = gcnt[(size_t)row * NSPLIT_B + s];
    const float* src = gcand + (size_t)row * (NSPLIT_B * SEG) + (size_t)s * SEG;
#pragma unroll 1
    for (int base = 0; base < cnt; base += 64) {
      int n = cnt - base; if (n > 64) n = 64;
      lst = merge_row(lst, src + base, n);
    }
  }
  out[(size_t)row * KSEL + lane] = lst;
}

// ---------------------------------------------------------------------------
extern "C" void kernel_launch(void* const* d_in, const int* in_sizes, int n_in,
                              void* d_out, int out_size, void* d_ws, size_t ws_size,
                              hipStream_t stream) {
  const float* x = (const float*)d_in[0];
  const float* b = (const float*)d_in[1];
  // d_in[2] = target (unused), d_in[3] = k (hardcoded 64)
  float* out = (float*)d_out;
  char* ws = (char*)d_ws;

  size_t off = 0;
  uint8_t* xh = (uint8_t*)(ws + off); off += (size_t)TOKENS * DMODEL;          // 4.2 MB
  uint8_t* bh = (uint8_t*)(ws + off); off += (size_t)VOCAB * DMODEL;           // 51.5 MB
  off = (off + 255) & ~(size_t)255;
  float* xsq = (float*)(ws + off); off += (size_t)TOKENS * sizeof(float);
  float* bsq = (float*)(ws + off); off += (((size_t)VOCAB * sizeof(float)) + 255) & ~(size_t)255;
  float* sample64 = (float*)(ws + off); off += (size_t)TOKENS * KSEL * sizeof(float);         // 1 MB
  int* gcnt = (int*)(ws + off); off += (size_t)TOKENS * NSPLIT_B * sizeof(int);               // 256 KB
  float* parts = (float*)(ws + off); off += (size_t)TOKENS * NSPLIT_A * KSEL * sizeof(float); // 16.8 MB
  float* gcand = (float*)(ws + off); off += (size_t)TOKENS * NSPLIT_B * SEG * sizeof(float);  // 67 MB

  prep_kernel<<<TOKENS + VOCAB, 256, 0, stream>>>(x, b, xh, bh, xsq, bsq);
  gemm_topk_sample<<<(TOKENS / BMS) * NSPLIT_A, 512, 0, stream>>>(xh, bh, xsq, bsq, parts);
  tau_reduce_kernel<<<TOKENS / 4, 256, 0, stream>>>(parts, sample64);
  gemm_filter_kernel<<<(TOKENS / BMF) * NSPLIT_B, 512, 0, stream>>>(xh, bh, xsq, bsq, sample64, gcand, gcnt);
  select_kernel<<<TOKENS / 4, 256, 0, stream>>>(gcand, gcnt, sample64, out);
}

// Round 14
// 657.261 us; speedup vs baseline: 1.2586x; 1.1008x over previous
//
#include <hip/hip_runtime.h>
#include <hip/hip_bf16.h>
#include <stdint.h>

#define TOKENS 4096
#define DMODEL 1024
#define VOCAB  50257
#define KSEL   64
#define BN 128
#define BK 64
#define BM 128
// pass A (sample): first 2048 cols, 16 splits x 128 cols, 512 blocks
#define NSPLIT_A 16
#define COLS_A   128
#define SAMPLE_END (NSPLIT_A * COLS_A)             // 2048
// pass B (filter): cols [2048, VOCAB), 24 splits, 768 blocks = 3/CU
#define NSPLIT_B 24
#define COLS_B (VOCAB - SAMPLE_END)                // 48209
#define COLS_PER ((COLS_B + NSPLIT_B - 1) / NSPLIT_B)  // 2009
#define SEG 128                                    // per (block,row) survivor cap
#define CAP 56
#define MERGE_THR 17
#define TSZ (BM * BK)                              // 8192 B per fp8 tile buf
#define INF __builtin_inff()

typedef unsigned short u16;
typedef long i64;
typedef __attribute__((ext_vector_type(4))) float f32x4;

#define GLOAD16(gp, lp) __builtin_amdgcn_global_load_lds( \
    (const __attribute__((address_space(1))) void*)(gp),  \
    (__attribute__((address_space(3))) void*)(lp), 16, 0, 0)
#define GLOAD4(gp, lp) __builtin_amdgcn_global_load_lds(  \
    (const __attribute__((address_space(1))) void*)(gp),  \
    (__attribute__((address_space(3))) void*)(lp), 4, 0, 0)

// counted-vmcnt barrier: keep younger staging loads in flight (T3/T4)
#define WAITB(N) do { asm volatile("s_waitcnt vmcnt(" #N ")" ::: "memory"); \
                      __builtin_amdgcn_s_barrier(); } while (0)
// LDS-visibility-only barrier: does NOT drain vmcnt
#define LBAR() do { asm volatile("s_waitcnt lgkmcnt(0)" ::: "memory"); \
                    __builtin_amdgcn_s_barrier(); } while (0)
// drain outstanding loads+stores (gfx9: stores count in vmcnt), no barrier
#define DRAIN_VM() asm volatile("s_waitcnt vmcnt(0)" ::: "memory")

// ---------------------------------------------------------------------------
// Kernel 1: x,b -> fp8 e4m3 + fp32 squared norms. 1 block/row.
// ---------------------------------------------------------------------------
__global__ __launch_bounds__(256) void prep_kernel(
    const float* __restrict__ x, const float* __restrict__ b,
    uint8_t* __restrict__ xh, uint8_t* __restrict__ bh,
    float* __restrict__ xsq, float* __restrict__ bsq) {
  int row = blockIdx.x;
  int tid = threadIdx.x;
  const float* src;
  uint8_t* dst;
  float* nrm;
  int r;
  if (row < TOKENS) {
    r = row; src = x + (size_t)r * DMODEL; dst = xh + (size_t)r * DMODEL; nrm = xsq;
  } else {
    r = row - TOKENS; src = b + (size_t)r * DMODEL; dst = bh + (size_t)r * DMODEL; nrm = bsq;
  }
  float4 v = reinterpret_cast<const float4*>(src)[tid];
  float s = v.x * v.x + v.y * v.y + v.z * v.z + v.w * v.w;
  uint32_t w = __builtin_amdgcn_cvt_pk_fp8_f32(v.x, v.y, 0, false);
  w = __builtin_amdgcn_cvt_pk_fp8_f32(v.z, v.w, w, true);
  reinterpret_cast<uint32_t*>(dst)[tid] = w;
#pragma unroll
  for (int j = 1; j < 64; j <<= 1) s += __shfl_xor(s, j);
  __shared__ float acc4[4];
  if ((tid & 63) == 0) acc4[tid >> 6] = s;
  __syncthreads();
  if (tid == 0) nrm[r] = acc4[0] + acc4[1] + acc4[2] + acc4[3];
}

// ---------------------------------------------------------------------------
// merge_row: sort <=64 candidates (asc), merge 64 smallest into sorted lstv.
// ---------------------------------------------------------------------------
__device__ __attribute__((noinline)) float merge_row(float lstv, const float* cb, int cnt) {
  const int lane = threadIdx.x & 63;
  float v0 = (lane < cnt) ? cb[lane] : INF;
#pragma unroll
  for (int k = 2; k <= 64; k <<= 1) {
#pragma unroll
    for (int j = k >> 1; j > 0; j >>= 1) {
      float p = __shfl_xor(v0, j);
      bool keepmin = (((lane & j) == 0) == ((lane & k) == 0));
      v0 = keepmin ? fminf(v0, p) : fmaxf(v0, p);
    }
  }
  float rev = __shfl(v0, 63 - lane);
  float m = fminf(lstv, rev);
#pragma unroll
  for (int j = 32; j > 0; j >>= 1) {
    float p = __shfl_xor(m, j);
    m = ((lane & j) == 0) ? fminf(m, p) : fmaxf(m, p);
  }
  return m;
}

// merge64: both sorted asc across 64 lanes -> sorted asc 64 smallest of union
__device__ __forceinline__ float merge64(float a, float b, int lane) {
  float rev = __shfl(b, 63 - lane);
  float m = fminf(a, rev);
#pragma unroll
  for (int j = 32; j > 0; j >>= 1) {
    float p = __shfl_xor(m, j);
    m = ((lane & j) == 0) ? fminf(m, p) : fmaxf(m, p);
  }
  return m;
}

// ===========================================================================
// Shared GEMM machinery (fp8, 128x128 tile, BK=64) — round-10 proven geometry
// ===========================================================================
#define STAGE_STEP(BB, KS) do {                        \
    GLOAD16(a_src + (KS), &As[(BB) + wave * 1024]);    \
    GLOAD16(b_src + (KS), &Bs[(BB) + wave * 1024]);    \
  } while (0)

#define MFMA8(a0_, a1_, b0_, b1_, b2_, b3_)                                           \
    acc[0][0] = __builtin_amdgcn_mfma_f32_16x16x32_fp8_fp8(a0_, b0_, acc[0][0], 0, 0, 0); \
    acc[0][1] = __builtin_amdgcn_mfma_f32_16x16x32_fp8_fp8(a0_, b1_, acc[0][1], 0, 0, 0); \
    acc[0][2] = __builtin_amdgcn_mfma_f32_16x16x32_fp8_fp8(a0_, b2_, acc[0][2], 0, 0, 0); \
    acc[0][3] = __builtin_amdgcn_mfma_f32_16x16x32_fp8_fp8(a0_, b3_, acc[0][3], 0, 0, 0); \
    acc[1][0] = __builtin_amdgcn_mfma_f32_16x16x32_fp8_fp8(a1_, b0_, acc[1][0], 0, 0, 0); \
    acc[1][1] = __builtin_amdgcn_mfma_f32_16x16x32_fp8_fp8(a1_, b1_, acc[1][1], 0, 0, 0); \
    acc[1][2] = __builtin_amdgcn_mfma_f32_16x16x32_fp8_fp8(a1_, b2_, acc[1][2], 0, 0, 0); \
    acc[1][3] = __builtin_amdgcn_mfma_f32_16x16x32_fp8_fp8(a1_, b3_, acc[1][3], 0, 0, 0);

#define LD8(arr, BB, off) (*reinterpret_cast<const i64*>(&(arr)[(BB) + (off)]))
#define COMPUTE_STEP(BB) do {                                                  \
    i64 a0 = LD8(As, BB, A00), a1 = LD8(As, BB, A10);                          \
    i64 b0 = LD8(Bs, BB, B00), b1 = LD8(Bs, BB, B10);                          \
    i64 b2 = LD8(Bs, BB, B20), b3 = LD8(Bs, BB, B30);                          \
    __builtin_amdgcn_s_setprio(1);                                             \
    MFMA8(a0, a1, b0, b1, b2, b3)                                              \
    __builtin_amdgcn_s_setprio(0);                                             \
    i64 a0b = LD8(As, BB, A01), a1b = LD8(As, BB, A11);                        \
    i64 b0b = LD8(Bs, BB, B01), b1b = LD8(Bs, BB, B11);                        \
    i64 b2b = LD8(Bs, BB, B21), b3b = LD8(Bs, BB, B31);                        \
    __builtin_amdgcn_s_setprio(1);                                             \
    MFMA8(a0b, a1b, b0b, b1b, b2b, b3b)                                        \
    __builtin_amdgcn_s_setprio(0);                                             \
  } while (0)

// swizzled LDS byte offset (XOR-16B, involution)
#define PO_DEF auto po = [&](int row, int c) {                                 \
    return row * 64 + ((((c >> 4) ^ ((row >> 1) & 3)) << 4) | (c & 15));       \
  };

#define GEOM_COMMON                                                            \
  const int g4 = lane >> 4, fr = lane & 15;                                    \
  const int wm = wave >> 1, wn = wave & 1;                                     \
  const int rj = g4 * 4;                                                       \
  PO_DEF                                                                       \
  const int c0 = g4 * 8, c1 = 32 + g4 * 8;                                     \
  const int rA0 = wm * 32 + fr, rA1 = rA0 + 16;                                \
  const int rB0 = wn * 64 + fr, rB1 = rB0 + 16, rB2 = rB0 + 32, rB3 = rB0 + 48;\
  const int A00 = po(rA0, c0), A01 = po(rA0, c1);                              \
  const int A10 = po(rA1, c0), A11 = po(rA1, c1);                              \
  const int B00 = po(rB0, c0), B01 = po(rB0, c1);                              \
  const int B10 = po(rB1, c0), B11 = po(rB1, c1);                              \
  const int B20 = po(rB2, c0), B21 = po(rB2, c1);                              \
  const int B30 = po(rB3, c0), B31 = po(rB3, c1);

// 16-step, 3-buffer, 2-ahead, 2 loads/step -> steady WAITB(2)  (proven)
#define K_PIPELINE3()                                                           \
    _Pragma("unroll 1")                                                         \
    for (int i = 0; i < 4; ++i) {                                               \
      const int ksb = i * 192;                                                  \
      WAITB(2); STAGE_STEP(2 * TSZ, ksb + 128); COMPUTE_STEP(0);                \
      WAITB(2); STAGE_STEP(0,       ksb + 192); COMPUTE_STEP(TSZ);              \
      WAITB(2); STAGE_STEP(TSZ,     ksb + 256); COMPUTE_STEP(2 * TSZ);          \
    }                                                                           \
    WAITB(2); STAGE_STEP(2 * TSZ, 896); COMPUTE_STEP(0);                        \
    WAITB(2); STAGE_STEP(0,       960); COMPUTE_STEP(TSZ);                      \
    WAITB(2);                           COMPUTE_STEP(2 * TSZ);                  \
    WAITB(0);                           COMPUTE_STEP(0);

// ---------------------------------------------------------------------------
// Kernel 2 (pass A): fused GEMM + exact streaming top-64 over the SAMPLE.
// 512 blocks (16 splits x 32 mtiles of 128 rows), 1 chunk each.
// ---------------------------------------------------------------------------
__global__ __launch_bounds__(512, 4) void gemm_topk_sample(
    const uint8_t* __restrict__ xh, const uint8_t* __restrict__ bh,
    const float* __restrict__ xsq, const float* __restrict__ bsqg,
    float* __restrict__ parts) {
  __shared__ uint8_t As[3 * TSZ];
  __shared__ uint8_t Bs[3 * TSZ];
  __shared__ float cbuf[BM][CAP];
  __shared__ float tau[BM];
  __shared__ int   ccnt[BM];
  __shared__ float xsq_s[BM];

  const int tid  = threadIdx.x;
  const int lane = tid & 63;
  const int wave = tid >> 6;
  const int xcd = blockIdx.x & 7, idx = blockIdx.x >> 3;
  const int mt  = xcd * 4 + (idx & 3);              // 0..31
  const int ns  = idx >> 2;                         // 0..15

  const int mrow0 = mt * BM;
  const int col0  = ns * COLS_A;

  const int stg_row = wave * 16 + (lane >> 2);
  const int stg_gran = ((lane & 3) ^ ((lane >> 3) & 3)) << 4;
  const uint8_t* a_src = xh + (size_t)(mrow0 + stg_row) * DMODEL + stg_gran;
  const uint8_t* b_src = bh + (size_t)(col0 + stg_row) * DMODEL + stg_gran;

  if (tid < BM) {
    xsq_s[tid] = xsq[mrow0 + tid];
    tau[tid] = INF;
    ccnt[tid] = 0;
  }
  STAGE_STEP(0, 0);
  STAGE_STEP(TSZ, BK);

  float lst[16];
#pragma unroll
  for (int i = 0; i < 16; ++i) lst[i] = INF;

  GEOM_COMMON
  const int r0 = wm * 32 + wn * 16;

  const int cbase = col0;
  f32x4 acc[2][4];
#pragma unroll
  for (int i = 0; i < 2; ++i)
#pragma unroll
    for (int j = 0; j < 4; ++j) acc[i][j] = (f32x4){0.f, 0.f, 0.f, 0.f};

  K_PIPELINE3()

#pragma unroll
  for (int p = 0; p < 4; ++p) {
    if (wn == (p & 1)) {
#pragma unroll
      for (int f2 = 0; f2 < 2; ++f2) {
        const int fn = (p >> 1) * 2 + f2;
        const int c = cbase + wn * 64 + fn * 16 + fr;
        const float bq = bsqg[c];
#pragma unroll
        for (int fm = 0; fm < 2; ++fm) {
#pragma unroll
          for (int j = 0; j < 4; ++j) {
            const int rl = wm * 32 + fm * 16 + rj + j;
            const float dist = xsq_s[rl] + bq - 2.0f * acc[fm][fn][j];
            if (dist < tau[rl]) {
              int ix = atomicAdd(&ccnt[rl], 1);
              if (ix < CAP) cbuf[rl][ix] = dist;
            }
          }
        }
      }
    }
    LBAR();
    const bool force = (p == 3);
#pragma unroll
    for (int rl16 = 0; rl16 < 16; ++rl16) {       // static idx (rule #20)
      const int r = r0 + rl16;
      const int cnt = ccnt[r];
      if (cnt >= MERGE_THR || (force && cnt > 0)) {
        float m = merge_row(lst[rl16], &cbuf[r][0], cnt);
        lst[rl16] = m;
        if (lane == 63) { tau[r] = m; ccnt[r] = 0; }
      }
    }
    LBAR();
  }

#pragma unroll
  for (int rl16 = 0; rl16 < 16; ++rl16) {
    parts[(size_t)(mrow0 + r0 + rl16) * (NSPLIT_A * KSEL) + ns * KSEL + lane] = lst[rl16];
  }
}

// ---------------------------------------------------------------------------
// Kernel 3: sample64[r][0..63] = sorted top-64 of sample (merge 16 lists).
// ---------------------------------------------------------------------------
__global__ __launch_bounds__(256) void tau_reduce_kernel(
    const float* __restrict__ parts, float* __restrict__ sample64) {
  const int lane = threadIdx.x & 63;
  const int row = blockIdx.x * 4 + (threadIdx.x >> 6);
  float v[16];
#pragma unroll
  for (int i = 0; i < 16; ++i)
    v[i] = parts[(size_t)row * (NSPLIT_A * KSEL) + i * KSEL + lane];
#pragma unroll
  for (int i = 0; i < 8; ++i) v[i] = merge64(v[i], v[i + 8], lane);
#pragma unroll
  for (int i = 0; i < 4; ++i) v[i] = merge64(v[i], v[i + 4], lane);
#pragma unroll
  for (int i = 0; i < 2; ++i) v[i] = merge64(v[i], v[i + 2], lane);
  v[0] = merge64(v[0], v[1], lane);
  sample64[(size_t)row * KSEL + lane] = v[0];
}

// ---------------------------------------------------------------------------
// Kernel 4 (pass B): PURE fp8 GEMM (round-10 geometry), 3-buf pipeline,
// 768 blocks = 3 blocks/CU (LDS 50.5KB). Survivors (dist < tau0) go to
// per-(block,row) private segments via LDS counters. Per-XCD mapping
// 8 mt x 12 ns keeps L2 footprint at ~2.5MB (A 1MB + B 1.5MB staggered).
// ---------------------------------------------------------------------------
__global__ __launch_bounds__(512, 4) void gemm_filter_kernel(
    const uint8_t* __restrict__ xh, const uint8_t* __restrict__ bh,
    const float* __restrict__ xsq, const float* __restrict__ bsqg,
    const float* __restrict__ sample64,
    float* __restrict__ gcand, int* __restrict__ gcnt) {
  __shared__ uint8_t As[3 * TSZ];    // 24KB
  __shared__ uint8_t Bs[3 * TSZ];    // 24KB
  __shared__ float bsq_s[2][BN];     // 1KB (parity by chunk)
  __shared__ float xsq_s[BM];        // 512B
  __shared__ float tau_s[BM];        // 512B
  __shared__ int   svcnt[BM];        // 512B
  // 50.5KB -> 3 blocks/CU (24 waves/CU)

  const int tid  = threadIdx.x;
  const int lane = tid & 63;
  const int wave = tid >> 6;
  // per-XCD 8 mt x 12 ns (bijective: xcd = (mt>>3)*2 + (ns>=12))
  const int xcd = blockIdx.x & 7, idx = blockIdx.x >> 3;   // idx 0..95
  const int mt  = ((xcd >> 1) << 3) + (idx & 7);           // 0..31
  const int ns  = (xcd & 1) * 12 + (idx >> 3);             // 0..23

  const int mrow0 = mt * BM;
  const int col0  = SAMPLE_END + ns * COLS_PER;
  const int col1  = (col0 + COLS_PER < VOCAB) ? (col0 + COLS_PER) : VOCAB;
  const int nchunk = (col1 - col0 + BN - 1) / BN;

  const int stg_row = wave * 16 + (lane >> 2);
  const int stg_gran = ((lane & 3) ^ ((lane >> 3) & 3)) << 4;
  const uint8_t* a_src = xh + (size_t)(mrow0 + stg_row) * DMODEL + stg_gran;
  int gc0 = col0 + stg_row; if (gc0 > VOCAB - 1) gc0 = VOCAB - 1;
  const uint8_t* b_src = bh + (size_t)gc0 * DMODEL + stg_gran;

#define STAGE_BSQ(CC) do {                                              \
    int c_ = col0 + (CC) * BN + lane;                                   \
    int cA_ = (c_ < VOCAB) ? c_ : (VOCAB - 1);                          \
    int cB_ = (c_ + 64 < VOCAB) ? (c_ + 64) : (VOCAB - 1);              \
    GLOAD4(bsqg + cA_, &bsq_s[(CC) & 1][0]);                            \
    GLOAD4(bsqg + cB_, &bsq_s[(CC) & 1][64]);                           \
  } while (0)

  if (tid < BM) {                     // plain loads BEFORE counted staging
    xsq_s[tid] = xsq[mrow0 + tid];
    tau_s[tid] = sample64[(size_t)(mrow0 + tid) * KSEL + (KSEL - 1)];
    svcnt[tid] = 0;
  }
  // chunk-0 prologue: bsq(2) + S0(2) + S1(2) = 6 outstanding
  STAGE_BSQ(0);
  STAGE_STEP(0, 0);
  STAGE_STEP(TSZ, BK);

  GEOM_COMMON
  float* seg_base = gcand + (size_t)mrow0 * (NSPLIT_B * SEG) + (size_t)ns * SEG;

#pragma unroll 1
  for (int ch = 0; ch < nchunk; ++ch) {
    const int cbase = col0 + ch * BN;
    f32x4 acc[2][4];
#pragma unroll
    for (int i = 0; i < 2; ++i)
#pragma unroll
      for (int j = 0; j < 4; ++j) acc[i][j] = (f32x4){0.f, 0.f, 0.f, 0.f};

    K_PIPELINE3()
    // WAITB(0) drained; barrier passed -> tiles + bsq_s readable.

    // ---- filter epilogue: dist < tau0 -> LDS-counted private segment ----
#pragma unroll
    for (int fn = 0; fn < 4; ++fn) {
      const int c = cbase + wn * 64 + fn * 16 + fr;
      const bool cv = (c < col1);
      const float bq = bsq_s[ch & 1][wn * 64 + fn * 16 + fr];
#pragma unroll
      for (int fm = 0; fm < 2; ++fm) {
#pragma unroll
        for (int j = 0; j < 4; ++j) {
          const int rl = wm * 32 + fm * 16 + rj + j;
          const float dist = xsq_s[rl] + bq - 2.0f * acc[fm][fn][j];
          if (cv && dist < tau_s[rl]) {
            int ix = atomicAdd(&svcnt[rl], 1);       // LDS atomic (rare: ~3%)
            if (ix < SEG)
              seg_base[(size_t)rl * (NSPLIT_B * SEG) + ix] = dist;
          }
        }
      }
    }
    DRAIN_VM();                       // retire stores: vmcnt ledger stays clean
    LBAR();                           // all waves past t15 (buf0/buf1 WAR-safe)
    if (ch + 1 < nchunk) {            // next-chunk prologue under epilogue tail
      STAGE_BSQ(ch + 1);
      int gcn = col0 + (ch + 1) * BN + stg_row;
      if (gcn > VOCAB - 1) gcn = VOCAB - 1;
      b_src = bh + (size_t)gcn * DMODEL + stg_gran;
      STAGE_STEP(0, 0);
      STAGE_STEP(TSZ, BK);
    }
  }

  LBAR();                             // all LDS atomics visible
  if (tid < BM) {
    int c = svcnt[tid]; if (c > SEG) c = SEG;
    gcnt[(size_t)(mrow0 + tid) * NSPLIT_B + ns] = c;
  }
}

// ---------------------------------------------------------------------------
// Kernel 5 (pass C): per row, top-64 = sample64 merged with all survivors
// from the 24 per-block segments. One wave per row.
// ---------------------------------------------------------------------------
__global__ __launch_bounds__(256) void select_kernel(
    const float* __restrict__ gcand, const int* __restrict__ gcnt,
    const float* __restrict__ sample64, float* __restrict__ out) {
  const int lane = threadIdx.x & 63;
  const int row = blockIdx.x * 4 + (threadIdx.x >> 6);
  float lst = sample64[(size_t)row * KSEL + lane];   // sorted asc
#pragma unroll 1
  for (int s = 0; s < NSPLIT_B; ++s) {
    int cnt = gcnt[(size_t)row * NSPLIT_B + s];
    const float* src = gcand + (size_t)row * (NSPLIT_B * SEG) + (size_t)s * SEG;
#pragma unroll 1
    for (int base = 0; base < cnt; base += 64) {
      int n = cnt - base; if (n > 64) n = 64;
      lst = merge_row(lst, src + base, n);
    }
  }
  out[(size_t)row * KSEL + lane] = lst;
}

// ---------------------------------------------------------------------------
extern "C" void kernel_launch(void* const* d_in, const int* in_sizes, int n_in,
                              void* d_out, int out_size, void* d_ws, size_t ws_size,
                              hipStream_t stream) {
  const float* x = (const float*)d_in[0];
  const float* b = (const float*)d_in[1];
  // d_in[2] = target (unused), d_in[3] = k (hardcoded 64)
  float* out = (float*)d_out;
  char* ws = (char*)d_ws;

  size_t off = 0;
  uint8_t* xh = (uint8_t*)(ws + off); off += (size_t)TOKENS * DMODEL;          // 4.2 MB
  uint8_t* bh = (uint8_t*)(ws + off); off += (size_t)VOCAB * DMODEL;           // 51.5 MB
  off = (off + 255) & ~(size_t)255;
  float* xsq = (float*)(ws + off); off += (size_t)TOKENS * sizeof(float);
  float* bsq = (float*)(ws + off); off += (((size_t)VOCAB * sizeof(float)) + 255) & ~(size_t)255;
  float* sample64 = (float*)(ws + off); off += (size_t)TOKENS * KSEL * sizeof(float);         // 1 MB
  int* gcnt = (int*)(ws + off); off += (size_t)TOKENS * NSPLIT_B * sizeof(int);               // 393 KB
  float* parts = (float*)(ws + off); off += (size_t)TOKENS * NSPLIT_A * KSEL * sizeof(float); // 16.8 MB
  float* gcand = (float*)(ws + off); off += (size_t)TOKENS * NSPLIT_B * SEG * sizeof(float);  // 50.3 MB

  prep_kernel<<<TOKENS + VOCAB, 256, 0, stream>>>(x, b, xh, bh, xsq, bsq);
  gemm_topk_sample<<<(TOKENS / BM) * NSPLIT_A, 512, 0, stream>>>(xh, bh, xsq, bsq, parts);
  tau_reduce_kernel<<<TOKENS / 4, 256, 0, stream>>>(parts, sample64);
  gemm_filter_kernel<<<(TOKENS / BM) * NSPLIT_B, 512, 0, stream>>>(xh, bh, xsq, bsq, sample64, gcand, gcnt);
  select_kernel<<<TOKENS / 4, 256, 0, stream>>>(gcand, gcnt, sample64, out);
}

// Round 15
// 544.216 us; speedup vs baseline: 1.5200x; 1.2077x over previous
//
#include <hip/hip_runtime.h>
#include <hip/hip_bf16.h>
#include <stdint.h>

#define TOKENS 4096
#define DMODEL 1024
#define VOCAB  50257
#define KSEL   64
#define BN 128
#define BK 64
#define BM 128
// pass A (sample): first 2048 cols -> raw dist matrix, then top-64 reduce
#define NSPLIT_A 16
#define COLS_A   128
#define SAMPLE_END (NSPLIT_A * COLS_A)             // 2048
// pass B (filter): cols [2048, VOCAB), 16 splits, 512 blocks  (round-10 exact)
#define NSPLIT_B 16
#define COLS_B (VOCAB - SAMPLE_END)                // 48209
#define COLS_PER ((COLS_B + NSPLIT_B - 1) / NSPLIT_B)  // 3014
#define SEG 256                                    // per (block,row) survivor cap
#define TSZ (BM * BK)                              // 8192 B per fp8 tile buf
#define INF __builtin_inff()

typedef unsigned short u16;
typedef long i64;
typedef __attribute__((ext_vector_type(4))) float f32x4;

#define GLOAD16(gp, lp) __builtin_amdgcn_global_load_lds( \
    (const __attribute__((address_space(1))) void*)(gp),  \
    (__attribute__((address_space(3))) void*)(lp), 16, 0, 0)
#define GLOAD4(gp, lp) __builtin_amdgcn_global_load_lds(  \
    (const __attribute__((address_space(1))) void*)(gp),  \
    (__attribute__((address_space(3))) void*)(lp), 4, 0, 0)

// counted-vmcnt barrier: keep younger staging loads in flight (T3/T4)
#define WAITB(N) do { asm volatile("s_waitcnt vmcnt(" #N ")" ::: "memory"); \
                      __builtin_amdgcn_s_barrier(); } while (0)
// LDS-visibility-only barrier: does NOT drain vmcnt
#define LBAR() do { asm volatile("s_waitcnt lgkmcnt(0)" ::: "memory"); \
                    __builtin_amdgcn_s_barrier(); } while (0)
// drain outstanding loads+stores (gfx9: stores count in vmcnt), no barrier
#define DRAIN_VM() asm volatile("s_waitcnt vmcnt(0)" ::: "memory")

// ---------------------------------------------------------------------------
// Kernel 1: x,b -> fp8 e4m3 + fp32 squared norms. 1 block/row.
// ---------------------------------------------------------------------------
__global__ __launch_bounds__(256) void prep_kernel(
    const float* __restrict__ x, const float* __restrict__ b,
    uint8_t* __restrict__ xh, uint8_t* __restrict__ bh,
    float* __restrict__ xsq, float* __restrict__ bsq) {
  int row = blockIdx.x;
  int tid = threadIdx.x;
  const float* src;
  uint8_t* dst;
  float* nrm;
  int r;
  if (row < TOKENS) {
    r = row; src = x + (size_t)r * DMODEL; dst = xh + (size_t)r * DMODEL; nrm = xsq;
  } else {
    r = row - TOKENS; src = b + (size_t)r * DMODEL; dst = bh + (size_t)r * DMODEL; nrm = bsq;
  }
  float4 v = reinterpret_cast<const float4*>(src)[tid];
  float s = v.x * v.x + v.y * v.y + v.z * v.z + v.w * v.w;
  uint32_t w = __builtin_amdgcn_cvt_pk_fp8_f32(v.x, v.y, 0, false);
  w = __builtin_amdgcn_cvt_pk_fp8_f32(v.z, v.w, w, true);
  reinterpret_cast<uint32_t*>(dst)[tid] = w;
#pragma unroll
  for (int j = 1; j < 64; j <<= 1) s += __shfl_xor(s, j);
  __shared__ float acc4[4];
  if ((tid & 63) == 0) acc4[tid >> 6] = s;
  __syncthreads();
  if (tid == 0) nrm[r] = acc4[0] + acc4[1] + acc4[2] + acc4[3];
}

// ---------------------------------------------------------------------------
// merge_row: sort <=64 candidates (asc), merge 64 smallest into sorted lstv.
// ---------------------------------------------------------------------------
__device__ __attribute__((noinline)) float merge_row(float lstv, const float* cb, int cnt) {
  const int lane = threadIdx.x & 63;
  float v0 = (lane < cnt) ? cb[lane] : INF;
#pragma unroll
  for (int k = 2; k <= 64; k <<= 1) {
#pragma unroll
    for (int j = k >> 1; j > 0; j >>= 1) {
      float p = __shfl_xor(v0, j);
      bool keepmin = (((lane & j) == 0) == ((lane & k) == 0));
      v0 = keepmin ? fminf(v0, p) : fmaxf(v0, p);
    }
  }
  float rev = __shfl(v0, 63 - lane);
  float m = fminf(lstv, rev);
#pragma unroll
  for (int j = 32; j > 0; j >>= 1) {
    float p = __shfl_xor(m, j);
    m = ((lane & j) == 0) ? fminf(m, p) : fmaxf(m, p);
  }
  return m;
}

// ===========================================================================
// Shared GEMM machinery (fp8, 128x128 tile, BK=64) — round-10 proven
// ===========================================================================
#define STAGE_STEP(BB, KS) do {                        \
    GLOAD16(a_src + (KS), &As[(BB) + wave * 1024]);    \
    GLOAD16(b_src + (KS), &Bs[(BB) + wave * 1024]);    \
  } while (0)

#define MFMA8(a0_, a1_, b0_, b1_, b2_, b3_)                                           \
    acc[0][0] = __builtin_amdgcn_mfma_f32_16x16x32_fp8_fp8(a0_, b0_, acc[0][0], 0, 0, 0); \
    acc[0][1] = __builtin_amdgcn_mfma_f32_16x16x32_fp8_fp8(a0_, b1_, acc[0][1], 0, 0, 0); \
    acc[0][2] = __builtin_amdgcn_mfma_f32_16x16x32_fp8_fp8(a0_, b2_, acc[0][2], 0, 0, 0); \
    acc[0][3] = __builtin_amdgcn_mfma_f32_16x16x32_fp8_fp8(a0_, b3_, acc[0][3], 0, 0, 0); \
    acc[1][0] = __builtin_amdgcn_mfma_f32_16x16x32_fp8_fp8(a1_, b0_, acc[1][0], 0, 0, 0); \
    acc[1][1] = __builtin_amdgcn_mfma_f32_16x16x32_fp8_fp8(a1_, b1_, acc[1][1], 0, 0, 0); \
    acc[1][2] = __builtin_amdgcn_mfma_f32_16x16x32_fp8_fp8(a1_, b2_, acc[1][2], 0, 0, 0); \
    acc[1][3] = __builtin_amdgcn_mfma_f32_16x16x32_fp8_fp8(a1_, b3_, acc[1][3], 0, 0, 0);

#define LD8(arr, BB, off) (*reinterpret_cast<const i64*>(&(arr)[(BB) + (off)]))
#define COMPUTE_STEP(BB) do {                                                  \
    i64 a0 = LD8(As, BB, A00), a1 = LD8(As, BB, A10);                          \
    i64 b0 = LD8(Bs, BB, B00), b1 = LD8(Bs, BB, B10);                          \
    i64 b2 = LD8(Bs, BB, B20), b3 = LD8(Bs, BB, B30);                          \
    __builtin_amdgcn_s_setprio(1);                                             \
    MFMA8(a0, a1, b0, b1, b2, b3)                                              \
    __builtin_amdgcn_s_setprio(0);                                             \
    i64 a0b = LD8(As, BB, A01), a1b = LD8(As, BB, A11);                        \
    i64 b0b = LD8(Bs, BB, B01), b1b = LD8(Bs, BB, B11);                        \
    i64 b2b = LD8(Bs, BB, B21), b3b = LD8(Bs, BB, B31);                        \
    __builtin_amdgcn_s_setprio(1);                                             \
    MFMA8(a0b, a1b, b0b, b1b, b2b, b3b)                                        \
    __builtin_amdgcn_s_setprio(0);                                             \
  } while (0)

// swizzled LDS byte offset (XOR-16B, involution)
#define PO_DEF auto po = [&](int row, int c) {                                 \
    return row * 64 + ((((c >> 4) ^ ((row >> 1) & 3)) << 4) | (c & 15));       \
  };

#define GEOM_COMMON                                                            \
  const int g4 = lane >> 4, fr = lane & 15;                                    \
  const int wm = wave >> 1, wn = wave & 1;                                     \
  const int rj = g4 * 4;                                                       \
  PO_DEF                                                                       \
  const int c0 = g4 * 8, c1 = 32 + g4 * 8;                                     \
  const int rA0 = wm * 32 + fr, rA1 = rA0 + 16;                                \
  const int rB0 = wn * 64 + fr, rB1 = rB0 + 16, rB2 = rB0 + 32, rB3 = rB0 + 48;\
  const int A00 = po(rA0, c0), A01 = po(rA0, c1);                              \
  const int A10 = po(rA1, c0), A11 = po(rA1, c1);                              \
  const int B00 = po(rB0, c0), B01 = po(rB0, c1);                              \
  const int B10 = po(rB1, c0), B11 = po(rB1, c1);                              \
  const int B20 = po(rB2, c0), B21 = po(rB2, c1);                              \
  const int B30 = po(rB3, c0), B31 = po(rB3, c1);

// 16-step, 3-buffer, 2-ahead, 2 loads/step -> steady WAITB(2)
#define K_PIPELINE3()                                                           \
    _Pragma("unroll 1")                                                         \
    for (int i = 0; i < 4; ++i) {                                               \
      const int ksb = i * 192;                                                  \
      WAITB(2); STAGE_STEP(2 * TSZ, ksb + 128); COMPUTE_STEP(0);                \
      WAITB(2); STAGE_STEP(0,       ksb + 192); COMPUTE_STEP(TSZ);              \
      WAITB(2); STAGE_STEP(TSZ,     ksb + 256); COMPUTE_STEP(2 * TSZ);          \
    }                                                                           \
    WAITB(2); STAGE_STEP(2 * TSZ, 896); COMPUTE_STEP(0);                        \
    WAITB(2); STAGE_STEP(0,       960); COMPUTE_STEP(TSZ);                      \
    WAITB(2);                           COMPUTE_STEP(2 * TSZ);                  \
    WAITB(0);                           COMPUTE_STEP(0);

// 16-step, 4-buffer, 3-ahead, 2 loads/step -> steady WAITB(4)  (round-10)
#define K_PIPELINE4()                                                           \
    _Pragma("unroll 1")                                                         \
    for (int i = 0; i < 3; ++i) {                                               \
      const int ksb = i * 256;                                                  \
      WAITB(4); STAGE_STEP(3 * TSZ, ksb + 192); COMPUTE_STEP(0);                \
      WAITB(4); STAGE_STEP(0,       ksb + 256); COMPUTE_STEP(TSZ);              \
      WAITB(4); STAGE_STEP(TSZ,     ksb + 320); COMPUTE_STEP(2 * TSZ);          \
      WAITB(4); STAGE_STEP(2 * TSZ, ksb + 384); COMPUTE_STEP(3 * TSZ);          \
    }                                                                           \
    WAITB(4); STAGE_STEP(3 * TSZ, 960); COMPUTE_STEP(0);      /* t=12 */        \
    WAITB(4);                           COMPUTE_STEP(TSZ);    /* t=13 */        \
    WAITB(2);                           COMPUTE_STEP(2 * TSZ);/* t=14 */        \
    WAITB(0);                           COMPUTE_STEP(3 * TSZ);/* t=15 */

// ---------------------------------------------------------------------------
// Kernel 2 (pass A1): PURE fp8 GEMM over cols [0, 2048); writes raw dist
// matrix sdist[4096][2048] f32. 512 blocks (16 ns x 32 mt), 1 chunk each.
// ---------------------------------------------------------------------------
__global__ __launch_bounds__(512, 4) void gemm_sample_dist(
    const uint8_t* __restrict__ xh, const uint8_t* __restrict__ bh,
    const float* __restrict__ xsq, const float* __restrict__ bsqg,
    float* __restrict__ sdist) {
  __shared__ uint8_t As[3 * TSZ];    // 24KB
  __shared__ uint8_t Bs[3 * TSZ];    // 24KB
  __shared__ float xsq_s[BM];

  const int tid  = threadIdx.x;
  const int lane = tid & 63;
  const int wave = tid >> 6;
  const int xcd = blockIdx.x & 7, idx = blockIdx.x >> 3;
  const int mt  = xcd * 4 + (idx & 3);              // 0..31
  const int ns  = idx >> 2;                         // 0..15

  const int mrow0 = mt * BM;
  const int col0  = ns * COLS_A;

  const int stg_row = wave * 16 + (lane >> 2);
  const int stg_gran = ((lane & 3) ^ ((lane >> 3) & 3)) << 4;
  const uint8_t* a_src = xh + (size_t)(mrow0 + stg_row) * DMODEL + stg_gran;
  const uint8_t* b_src = bh + (size_t)(col0 + stg_row) * DMODEL + stg_gran;

  if (tid < BM) xsq_s[tid] = xsq[mrow0 + tid];     // plain load before staging
  STAGE_STEP(0, 0);
  STAGE_STEP(TSZ, BK);

  GEOM_COMMON

  f32x4 acc[2][4];
#pragma unroll
  for (int i = 0; i < 2; ++i)
#pragma unroll
    for (int j = 0; j < 4; ++j) acc[i][j] = (f32x4){0.f, 0.f, 0.f, 0.f};

  K_PIPELINE3()

  // epilogue: dist = xsq + bsq - 2ab -> sdist (16-col segments, coalesced)
#pragma unroll
  for (int fn = 0; fn < 4; ++fn) {
    const int c = col0 + wn * 64 + fn * 16 + fr;
    const float bq = bsqg[c];
#pragma unroll
    for (int fm = 0; fm < 2; ++fm) {
#pragma unroll
      for (int j = 0; j < 4; ++j) {
        const int rl = wm * 32 + fm * 16 + rj + j;
        sdist[(size_t)(mrow0 + rl) * SAMPLE_END + c] =
            xsq_s[rl] + bq - 2.0f * acc[fm][fn][j];
      }
    }
  }
}

// ---------------------------------------------------------------------------
// Kernel 3 (pass A2): sample64[r] = sorted top-64 of sdist row (32 merges).
// One wave per row.
// ---------------------------------------------------------------------------
__global__ __launch_bounds__(256) void sample_reduce_kernel(
    const float* __restrict__ sdist, float* __restrict__ sample64) {
  const int lane = threadIdx.x & 63;
  const int row = blockIdx.x * 4 + (threadIdx.x >> 6);
  const float* src = sdist + (size_t)row * SAMPLE_END;
  float lst = INF;
#pragma unroll 1
  for (int base = 0; base < SAMPLE_END; base += 64)
    lst = merge_row(lst, src + base, 64);
  sample64[(size_t)row * KSEL + lane] = lst;
}

// ---------------------------------------------------------------------------
// Kernel 4 (pass B): PURE fp8 GEMM over cols [2048, VOCAB)  — ROUND-10 EXACT.
// Survivors (dist < tau0) -> per-(block,row) private segments, LDS counters.
// 512 blocks, 4-buf deep pipeline, 2 blocks/CU (67KB LDS).
// ---------------------------------------------------------------------------
__global__ __launch_bounds__(512, 4) void gemm_filter_kernel(
    const uint8_t* __restrict__ xh, const uint8_t* __restrict__ bh,
    const float* __restrict__ xsq, const float* __restrict__ bsqg,
    const float* __restrict__ sample64,
    float* __restrict__ gcand, int* __restrict__ gcnt) {
  __shared__ uint8_t As[4 * TSZ];    // 32KB
  __shared__ uint8_t Bs[4 * TSZ];    // 32KB
  __shared__ float bsq_s[2][BN];     // 1KB (parity by chunk)
  __shared__ float xsq_s[BM];
  __shared__ float tau_s[BM];
  __shared__ int   svcnt[BM];        // per-row survivor counters (LDS atomics)
  // ~67KB -> 2 blocks/CU

  const int tid  = threadIdx.x;
  const int lane = tid & 63;
  const int wave = tid >> 6;
  // round-10 proven mapping: each XCD owns 4 mtiles -> A panel 512KB L2-resident
  const int xcd = blockIdx.x & 7, idx = blockIdx.x >> 3;
  const int mt  = xcd * 4 + (idx & 3);              // 0..31
  const int ns  = idx >> 2;                         // 0..15

  const int mrow0 = mt * BM;
  const int col0  = SAMPLE_END + ns * COLS_PER;
  const int col1  = (col0 + COLS_PER < VOCAB) ? (col0 + COLS_PER) : VOCAB;
  const int nchunk = (col1 - col0 + BN - 1) / BN;

  const int stg_row = wave * 16 + (lane >> 2);
  const int stg_gran = ((lane & 3) ^ ((lane >> 3) & 3)) << 4;
  const uint8_t* a_src = xh + (size_t)(mrow0 + stg_row) * DMODEL + stg_gran;
  int gc0 = col0 + stg_row; if (gc0 > VOCAB - 1) gc0 = VOCAB - 1;
  const uint8_t* b_src = bh + (size_t)gc0 * DMODEL + stg_gran;

#define STAGE_BSQ(CC) do {                                              \
    int c_ = col0 + (CC) * BN + lane;                                   \
    int cA_ = (c_ < VOCAB) ? c_ : (VOCAB - 1);                          \
    int cB_ = (c_ + 64 < VOCAB) ? (c_ + 64) : (VOCAB - 1);              \
    GLOAD4(bsqg + cA_, &bsq_s[(CC) & 1][0]);                            \
    GLOAD4(bsqg + cB_, &bsq_s[(CC) & 1][64]);                           \
  } while (0)

  if (tid < BM) {                     // plain loads BEFORE counted staging
    xsq_s[tid] = xsq[mrow0 + tid];
    tau_s[tid] = sample64[(size_t)(mrow0 + tid) * KSEL + (KSEL - 1)];
    svcnt[tid] = 0;
  }
  // chunk-0 prologue: bsq(2) + S0(2) + S1(2) + S2(2) = 8 outstanding
  STAGE_BSQ(0);
  STAGE_STEP(0, 0);
  STAGE_STEP(TSZ, BK);
  STAGE_STEP(2 * TSZ, 2 * BK);

  GEOM_COMMON
  float* seg_base = gcand + (size_t)mrow0 * (NSPLIT_B * SEG) + (size_t)ns * SEG;

#pragma unroll 1
  for (int ch = 0; ch < nchunk; ++ch) {
    const int cbase = col0 + ch * BN;
    f32x4 acc[2][4];
#pragma unroll
    for (int i = 0; i < 2; ++i)
#pragma unroll
      for (int j = 0; j < 4; ++j) acc[i][j] = (f32x4){0.f, 0.f, 0.f, 0.f};

    K_PIPELINE4()
    // WAITB(0) drained; barrier passed -> tiles/bsq_s readable.

    // ---- filter epilogue: dist < tau0 -> LDS-counted private segment ----
#pragma unroll
    for (int fn = 0; fn < 4; ++fn) {
      const int c = cbase + wn * 64 + fn * 16 + fr;
      const bool cv = (c < col1);
      const float bq = bsq_s[ch & 1][wn * 64 + fn * 16 + fr];
#pragma unroll
      for (int fm = 0; fm < 2; ++fm) {
#pragma unroll
        for (int j = 0; j < 4; ++j) {
          const int rl = wm * 32 + fm * 16 + rj + j;
          const float dist = xsq_s[rl] + bq - 2.0f * acc[fm][fn][j];
          if (cv && dist < tau_s[rl]) {
            int ix = atomicAdd(&svcnt[rl], 1);       // LDS atomic (rare: ~3%)
            if (ix < SEG)
              seg_base[(size_t)rl * (NSPLIT_B * SEG) + ix] = dist;
          }
        }
      }
    }
    DRAIN_VM();                       // retire stores: keeps vmcnt ledger clean
    if (ch + 1 < nchunk) {            // next-chunk prologue (WAR-safe: all
      STAGE_BSQ(ch + 1);              // waves passed t=13/14/15 barriers)
      int gcn = cbase + BN + stg_row;
      if (gcn > VOCAB - 1) gcn = VOCAB - 1;
      b_src = bh + (size_t)gcn * DMODEL + stg_gran;
      STAGE_STEP(0, 0);
      STAGE_STEP(TSZ, BK);
      STAGE_STEP(2 * TSZ, 2 * BK);
    }
  }

  LBAR();                             // all LDS atomics visible
  if (tid < BM) {
    int c = svcnt[tid]; if (c > SEG) c = SEG;
    gcnt[(size_t)(mrow0 + tid) * NSPLIT_B + ns] = c;
  }
}

// ---------------------------------------------------------------------------
// Kernel 5 (pass C): per row, top-64 = sample64 merged with all survivors
// from the 16 per-block segments. One wave per row.
// ---------------------------------------------------------------------------
__global__ __launch_bounds__(256) void select_kernel(
    const float* __restrict__ gcand, const int* __restrict__ gcnt,
    const float* __restrict__ sample64, float* __restrict__ out) {
  const int lane = threadIdx.x & 63;
  const int row = blockIdx.x * 4 + (threadIdx.x >> 6);
  float lst = sample64[(size_t)row * KSEL + lane];   // sorted asc
#pragma unroll 1
  for (int s = 0; s < NSPLIT_B; ++s) {
    int cnt = gcnt[(size_t)row * NSPLIT_B + s];
    const float* src = gcand + (size_t)row * (NSPLIT_B * SEG) + (size_t)s * SEG;
#pragma unroll 1
    for (int base = 0; base < cnt; base += 64) {
      int n = cnt - base; if (n > 64) n = 64;
      lst = merge_row(lst, src + base, n);
    }
  }
  out[(size_t)row * KSEL + lane] = lst;
}

// ---------------------------------------------------------------------------
extern "C" void kernel_launch(void* const* d_in, const int* in_sizes, int n_in,
                              void* d_out, int out_size, void* d_ws, size_t ws_size,
                              hipStream_t stream) {
  const float* x = (const float*)d_in[0];
  const float* b = (const float*)d_in[1];
  // d_in[2] = target (unused), d_in[3] = k (hardcoded 64)
  float* out = (float*)d_out;
  char* ws = (char*)d_ws;

  size_t off = 0;
  uint8_t* xh = (uint8_t*)(ws + off); off += (size_t)TOKENS * DMODEL;          // 4.2 MB
  uint8_t* bh = (uint8_t*)(ws + off); off += (size_t)VOCAB * DMODEL;           // 51.5 MB
  off = (off + 255) & ~(size_t)255;
  float* xsq = (float*)(ws + off); off += (size_t)TOKENS * sizeof(float);
  float* bsq = (float*)(ws + off); off += (((size_t)VOCAB * sizeof(float)) + 255) & ~(size_t)255;
  float* sample64 = (float*)(ws + off); off += (size_t)TOKENS * KSEL * sizeof(float);         // 1 MB
  int* gcnt = (int*)(ws + off); off += (size_t)TOKENS * NSPLIT_B * sizeof(int);               // 256 KB
  float* sdist = (float*)(ws + off); off += (size_t)TOKENS * SAMPLE_END * sizeof(float);      // 33.5 MB
  float* gcand = (float*)(ws + off); off += (size_t)TOKENS * NSPLIT_B * SEG * sizeof(float);  // 67 MB

  prep_kernel<<<TOKENS + VOCAB, 256, 0, stream>>>(x, b, xh, bh, xsq, bsq);
  gemm_sample_dist<<<(TOKENS / BM) * NSPLIT_A, 512, 0, stream>>>(xh, bh, xsq, bsq, sdist);
  sample_reduce_kernel<<<TOKENS / 4, 256, 0, stream>>>(sdist, sample64);
  gemm_filter_kernel<<<(TOKENS / BM) * NSPLIT_B, 512, 0, stream>>>(xh, bh, xsq, bsq, sample64, gcand, gcnt);
  select_kernel<<<TOKENS / 4, 256, 0, stream>>>(gcand, gcnt, sample64, out);
}

// Round 16
// 520.946 us; speedup vs baseline: 1.5879x; 1.0447x over previous
//
#include <hip/hip_runtime.h>
#include <hip/hip_bf16.h>
#include <stdint.h>

#define TOKENS 4096
#define DMODEL 1024
#define VOCAB  50257
#define KSEL   64
#define BN 128
#define BK 64
#define BM 128
// pass A (sample): first 2048 cols -> raw dist matrix, then top-64 reduce
#define NSPLIT_A 16
#define COLS_A   128
#define SAMPLE_END (NSPLIT_A * COLS_A)             // 2048
// pass B (filter): cols [2048, VOCAB), 16 splits, 512 blocks
#define NSPLIT_B 16
#define COLS_B (VOCAB - SAMPLE_END)                // 48209
#define COLS_PER ((COLS_B + NSPLIT_B - 1) / NSPLIT_B)  // 3014
#define SEG 256                                    // per (block,row) survivor cap
#define TSZ (BM * BK)                              // 8192 B per fp8 tile buf
#define INF __builtin_inff()

typedef unsigned short u16;
typedef long i64;
typedef __attribute__((ext_vector_type(2))) long i64x2;
typedef __attribute__((ext_vector_type(4))) float f32x4;

#define GLOAD16(gp, lp) __builtin_amdgcn_global_load_lds( \
    (const __attribute__((address_space(1))) void*)(gp),  \
    (__attribute__((address_space(3))) void*)(lp), 16, 0, 0)
#define GLOAD4(gp, lp) __builtin_amdgcn_global_load_lds(  \
    (const __attribute__((address_space(1))) void*)(gp),  \
    (__attribute__((address_space(3))) void*)(lp), 4, 0, 0)

// counted-vmcnt barrier: keep younger staging loads in flight (T3/T4)
#define WAITB(N) do { asm volatile("s_waitcnt vmcnt(" #N ")" ::: "memory"); \
                      __builtin_amdgcn_s_barrier(); } while (0)
// LDS-visibility-only barrier: does NOT drain vmcnt
#define LBAR() do { asm volatile("s_waitcnt lgkmcnt(0)" ::: "memory"); \
                    __builtin_amdgcn_s_barrier(); } while (0)
// drain outstanding loads+stores (gfx9: stores count in vmcnt), no barrier
#define DRAIN_VM() asm volatile("s_waitcnt vmcnt(0)" ::: "memory")

// ---------------------------------------------------------------------------
// Kernel 1: x,b -> fp8 e4m3 + fp32 squared norms. 1 block/row.
// ---------------------------------------------------------------------------
__global__ __launch_bounds__(256) void prep_kernel(
    const float* __restrict__ x, const float* __restrict__ b,
    uint8_t* __restrict__ xh, uint8_t* __restrict__ bh,
    float* __restrict__ xsq, float* __restrict__ bsq) {
  int row = blockIdx.x;
  int tid = threadIdx.x;
  const float* src;
  uint8_t* dst;
  float* nrm;
  int r;
  if (row < TOKENS) {
    r = row; src = x + (size_t)r * DMODEL; dst = xh + (size_t)r * DMODEL; nrm = xsq;
  } else {
    r = row - TOKENS; src = b + (size_t)r * DMODEL; dst = bh + (size_t)r * DMODEL; nrm = bsq;
  }
  float4 v = reinterpret_cast<const float4*>(src)[tid];
  float s = v.x * v.x + v.y * v.y + v.z * v.z + v.w * v.w;
  uint32_t w = __builtin_amdgcn_cvt_pk_fp8_f32(v.x, v.y, 0, false);
  w = __builtin_amdgcn_cvt_pk_fp8_f32(v.z, v.w, w, true);
  reinterpret_cast<uint32_t*>(dst)[tid] = w;
#pragma unroll
  for (int j = 1; j < 64; j <<= 1) s += __shfl_xor(s, j);
  __shared__ float acc4[4];
  if ((tid & 63) == 0) acc4[tid >> 6] = s;
  __syncthreads();
  if (tid == 0) nrm[r] = acc4[0] + acc4[1] + acc4[2] + acc4[3];
}

// ---------------------------------------------------------------------------
// merge_row: sort <=64 candidates (asc), merge 64 smallest into sorted lstv.
// ---------------------------------------------------------------------------
__device__ __attribute__((noinline)) float merge_row(float lstv, const float* cb, int cnt) {
  const int lane = threadIdx.x & 63;
  float v0 = (lane < cnt) ? cb[lane] : INF;
#pragma unroll
  for (int k = 2; k <= 64; k <<= 1) {
#pragma unroll
    for (int j = k >> 1; j > 0; j >>= 1) {
      float p = __shfl_xor(v0, j);
      bool keepmin = (((lane & j) == 0) == ((lane & k) == 0));
      v0 = keepmin ? fminf(v0, p) : fmaxf(v0, p);
    }
  }
  float rev = __shfl(v0, 63 - lane);
  float m = fminf(lstv, rev);
#pragma unroll
  for (int j = 32; j > 0; j >>= 1) {
    float p = __shfl_xor(m, j);
    m = ((lane & j) == 0) ? fminf(m, p) : fmaxf(m, p);
  }
  return m;
}

// ===========================================================================
// Shared GEMM machinery (fp8, 128x128 tile, BK=64).
// LDS layout per 128-row tile (8KB): 64 lines of 128B (row pair 2L,2L+1);
// 8 granule slots/line; phys slot = logical ^ (L&7), logical = (row&1)*4 + g
// (g = k-granule: global k-bytes [16g,16g+16) of the row). Read side: ONE
// ds_read_b128 per operand-row; MFMA1 consumes the low 8B (k [16g4,+8)),
// MFMA2 the high 8B (k [16g4+8,+8)) — each k counted once, A/B consistent.
// ===========================================================================
#define STAGE_STEP(BB, KS) do {                        \
    GLOAD16(a_src + (KS), &As[(BB) + wave * 1024]);    \
    GLOAD16(b_src + (KS), &Bs[(BB) + wave * 1024]);    \
  } while (0)

// staging source geometry (pre-swizzled; dest is linear tid*16):
//   l_log = (lane&7) ^ (lane>>3); row = wave*16 + 2*(lane>>3) + (l_log>>2);
//   gran byte = (l_log&3)*16
#define STG_GEOM                                                   \
  const int l_log = (lane & 7) ^ (lane >> 3);                      \
  const int stg_row = wave * 16 + ((lane >> 3) << 1) + (l_log >> 2); \
  const int stg_gran = (l_log & 3) << 4;

#define MFMA8(a0_, a1_, b0_, b1_, b2_, b3_)                                           \
    acc[0][0] = __builtin_amdgcn_mfma_f32_16x16x32_fp8_fp8(a0_, b0_, acc[0][0], 0, 0, 0); \
    acc[0][1] = __builtin_amdgcn_mfma_f32_16x16x32_fp8_fp8(a0_, b1_, acc[0][1], 0, 0, 0); \
    acc[0][2] = __builtin_amdgcn_mfma_f32_16x16x32_fp8_fp8(a0_, b2_, acc[0][2], 0, 0, 0); \
    acc[0][3] = __builtin_amdgcn_mfma_f32_16x16x32_fp8_fp8(a0_, b3_, acc[0][3], 0, 0, 0); \
    acc[1][0] = __builtin_amdgcn_mfma_f32_16x16x32_fp8_fp8(a1_, b0_, acc[1][0], 0, 0, 0); \
    acc[1][1] = __builtin_amdgcn_mfma_f32_16x16x32_fp8_fp8(a1_, b1_, acc[1][1], 0, 0, 0); \
    acc[1][2] = __builtin_amdgcn_mfma_f32_16x16x32_fp8_fp8(a1_, b2_, acc[1][2], 0, 0, 0); \
    acc[1][3] = __builtin_amdgcn_mfma_f32_16x16x32_fp8_fp8(a1_, b3_, acc[1][3], 0, 0, 0);

#define LD16(arr, BB, off) (*reinterpret_cast<const i64x2*>(&(arr)[(BB) + (off)]))
#define COMPUTE_STEP(BB) do {                                                  \
    i64x2 va0 = LD16(As, BB, A0), va1 = LD16(As, BB, A1);                      \
    i64x2 vb0 = LD16(Bs, BB, B0), vb1 = LD16(Bs, BB, B1);                      \
    i64x2 vb2 = LD16(Bs, BB, B2), vb3 = LD16(Bs, BB, B3);                      \
    __builtin_amdgcn_s_setprio(1);                                             \
    MFMA8(va0.x, va1.x, vb0.x, vb1.x, vb2.x, vb3.x)                            \
    __builtin_amdgcn_s_setprio(0);                                             \
    __builtin_amdgcn_s_setprio(1);                                             \
    MFMA8(va0.y, va1.y, vb0.y, vb1.y, vb2.y, vb3.y)                            \
    __builtin_amdgcn_s_setprio(0);                                             \
  } while (0)

// read-side swizzled b128 byte offset for operand row r, k-granule g4
#define GEOM_COMMON                                                            \
  const int g4 = lane >> 4, fr = lane & 15;                                    \
  const int wm = wave >> 1, wn = wave & 1;                                     \
  const int rj = g4 * 4;                                                       \
  auto ao = [&](int r) {                                                       \
    return (r >> 1) * 128 + (((((r) & 1) << 2) + g4) ^ ((r >> 1) & 7)) * 16;   \
  };                                                                           \
  const int A0 = ao(wm * 32 + fr),      A1 = ao(wm * 32 + 16 + fr);            \
  const int B0 = ao(wn * 64 + fr),      B1 = ao(wn * 64 + 16 + fr);            \
  const int B2 = ao(wn * 64 + 32 + fr), B3 = ao(wn * 64 + 48 + fr);

// 16-step, 3-buffer, 2-ahead, 2 loads/step -> steady WAITB(2)
#define K_PIPELINE3()                                                           \
    _Pragma("unroll 1")                                                         \
    for (int i = 0; i < 4; ++i) {                                               \
      const int ksb = i * 192;                                                  \
      WAITB(2); STAGE_STEP(2 * TSZ, ksb + 128); COMPUTE_STEP(0);                \
      WAITB(2); STAGE_STEP(0,       ksb + 192); COMPUTE_STEP(TSZ);              \
      WAITB(2); STAGE_STEP(TSZ,     ksb + 256); COMPUTE_STEP(2 * TSZ);          \
    }                                                                           \
    WAITB(2); STAGE_STEP(2 * TSZ, 896); COMPUTE_STEP(0);                        \
    WAITB(2); STAGE_STEP(0,       960); COMPUTE_STEP(TSZ);                      \
    WAITB(2);                           COMPUTE_STEP(2 * TSZ);                  \
    WAITB(0);                           COMPUTE_STEP(0);

// 16-step, 4-buffer, 3-ahead, 2 loads/step -> steady WAITB(4)  (round-10)
#define K_PIPELINE4()                                                           \
    _Pragma("unroll 1")                                                         \
    for (int i = 0; i < 3; ++i) {                                               \
      const int ksb = i * 256;                                                  \
      WAITB(4); STAGE_STEP(3 * TSZ, ksb + 192); COMPUTE_STEP(0);                \
      WAITB(4); STAGE_STEP(0,       ksb + 256); COMPUTE_STEP(TSZ);              \
      WAITB(4); STAGE_STEP(TSZ,     ksb + 320); COMPUTE_STEP(2 * TSZ);          \
      WAITB(4); STAGE_STEP(2 * TSZ, ksb + 384); COMPUTE_STEP(3 * TSZ);          \
    }                                                                           \
    WAITB(4); STAGE_STEP(3 * TSZ, 960); COMPUTE_STEP(0);      /* t=12 */        \
    WAITB(4);                           COMPUTE_STEP(TSZ);    /* t=13 */        \
    WAITB(2);                           COMPUTE_STEP(2 * TSZ);/* t=14 */        \
    WAITB(0);                           COMPUTE_STEP(3 * TSZ);/* t=15 */

// ---------------------------------------------------------------------------
// Kernel 2 (pass A1): PURE fp8 GEMM over cols [0, 2048); writes raw dist
// matrix sdist[4096][2048] f32. 512 blocks (16 ns x 32 mt), 1 chunk each.
// ---------------------------------------------------------------------------
__global__ __launch_bounds__(512, 4) void gemm_sample_dist(
    const uint8_t* __restrict__ xh, const uint8_t* __restrict__ bh,
    const float* __restrict__ xsq, const float* __restrict__ bsqg,
    float* __restrict__ sdist) {
  __shared__ __align__(16) uint8_t As[3 * TSZ];    // 24KB
  __shared__ __align__(16) uint8_t Bs[3 * TSZ];    // 24KB
  __shared__ float xsq_s[BM];

  const int tid  = threadIdx.x;
  const int lane = tid & 63;
  const int wave = tid >> 6;
  const int xcd = blockIdx.x & 7, idx = blockIdx.x >> 3;
  const int mt  = xcd * 4 + (idx & 3);              // 0..31
  const int ns  = idx >> 2;                         // 0..15

  const int mrow0 = mt * BM;
  const int col0  = ns * COLS_A;

  STG_GEOM
  const uint8_t* a_src = xh + (size_t)(mrow0 + stg_row) * DMODEL + stg_gran;
  const uint8_t* b_src = bh + (size_t)(col0 + stg_row) * DMODEL + stg_gran;

  if (tid < BM) xsq_s[tid] = xsq[mrow0 + tid];     // plain load before staging
  STAGE_STEP(0, 0);
  STAGE_STEP(TSZ, BK);

  GEOM_COMMON

  f32x4 acc[2][4];
#pragma unroll
  for (int i = 0; i < 2; ++i)
#pragma unroll
    for (int j = 0; j < 4; ++j) acc[i][j] = (f32x4){0.f, 0.f, 0.f, 0.f};

  K_PIPELINE3()

  // epilogue: dist = xsq + bsq - 2ab -> sdist (16-col segments, coalesced)
#pragma unroll
  for (int fn = 0; fn < 4; ++fn) {
    const int c = col0 + wn * 64 + fn * 16 + fr;
    const float bq = bsqg[c];
#pragma unroll
    for (int fm = 0; fm < 2; ++fm) {
#pragma unroll
      for (int j = 0; j < 4; ++j) {
        const int rl = wm * 32 + fm * 16 + rj + j;
        sdist[(size_t)(mrow0 + rl) * SAMPLE_END + c] =
            xsq_s[rl] + bq - 2.0f * acc[fm][fn][j];
      }
    }
  }
}

// ---------------------------------------------------------------------------
// Kernel 3 (pass A2): sample64[r] = sorted top-64 of sdist row (32 merges).
// One wave per row.
// ---------------------------------------------------------------------------
__global__ __launch_bounds__(256) void sample_reduce_kernel(
    const float* __restrict__ sdist, float* __restrict__ sample64) {
  const int lane = threadIdx.x & 63;
  const int row = blockIdx.x * 4 + (threadIdx.x >> 6);
  const float* src = sdist + (size_t)row * SAMPLE_END;
  float lst = INF;
#pragma unroll 1
  for (int base = 0; base < SAMPLE_END; base += 64)
    lst = merge_row(lst, src + base, 64);
  sample64[(size_t)row * KSEL + lane] = lst;
}

// ---------------------------------------------------------------------------
// Kernel 4 (pass B): PURE fp8 GEMM over cols [2048, VOCAB).
// Survivors (dist < tau0) -> per-(block,row) private segments, LDS counters.
// 512 blocks, 4-buf deep pipeline, 2 blocks/CU (67KB LDS).
// ---------------------------------------------------------------------------
__global__ __launch_bounds__(512, 4) void gemm_filter_kernel(
    const uint8_t* __restrict__ xh, const uint8_t* __restrict__ bh,
    const float* __restrict__ xsq, const float* __restrict__ bsqg,
    const float* __restrict__ sample64,
    float* __restrict__ gcand, int* __restrict__ gcnt) {
  __shared__ __align__(16) uint8_t As[4 * TSZ];    // 32KB
  __shared__ __align__(16) uint8_t Bs[4 * TSZ];    // 32KB
  __shared__ float bsq_s[2][BN];     // 1KB (parity by chunk)
  __shared__ float xsq_s[BM];
  __shared__ float tau_s[BM];
  __shared__ int   svcnt[BM];        // per-row survivor counters (LDS atomics)
  // ~67KB -> 2 blocks/CU

  const int tid  = threadIdx.x;
  const int lane = tid & 63;
  const int wave = tid >> 6;
  // round-10 proven mapping: each XCD owns 4 mtiles -> A panel 512KB L2-resident
  const int xcd = blockIdx.x & 7, idx = blockIdx.x >> 3;
  const int mt  = xcd * 4 + (idx & 3);              // 0..31
  const int ns  = idx >> 2;                         // 0..15

  const int mrow0 = mt * BM;
  const int col0  = SAMPLE_END + ns * COLS_PER;
  const int col1  = (col0 + COLS_PER < VOCAB) ? (col0 + COLS_PER) : VOCAB;
  const int nchunk = (col1 - col0 + BN - 1) / BN;

  STG_GEOM
  const uint8_t* a_src = xh + (size_t)(mrow0 + stg_row) * DMODEL + stg_gran;
  int gc0 = col0 + stg_row; if (gc0 > VOCAB - 1) gc0 = VOCAB - 1;
  const uint8_t* b_src = bh + (size_t)gc0 * DMODEL + stg_gran;

#define STAGE_BSQ(CC) do {                                              \
    int c_ = col0 + (CC) * BN + lane;                                   \
    int cA_ = (c_ < VOCAB) ? c_ : (VOCAB - 1);                          \
    int cB_ = (c_ + 64 < VOCAB) ? (c_ + 64) : (VOCAB - 1);              \
    GLOAD4(bsqg + cA_, &bsq_s[(CC) & 1][0]);                            \
    GLOAD4(bsqg + cB_, &bsq_s[(CC) & 1][64]);                           \
  } while (0)

  if (tid < BM) {                     // plain loads BEFORE counted staging
    xsq_s[tid] = xsq[mrow0 + tid];
    tau_s[tid] = sample64[(size_t)(mrow0 + tid) * KSEL + (KSEL - 1)];
    svcnt[tid] = 0;
  }
  // chunk-0 prologue: bsq(2) + S0(2) + S1(2) + S2(2) = 8 outstanding
  STAGE_BSQ(0);
  STAGE_STEP(0, 0);
  STAGE_STEP(TSZ, BK);
  STAGE_STEP(2 * TSZ, 2 * BK);

  GEOM_COMMON
  float* seg_base = gcand + (size_t)mrow0 * (NSPLIT_B * SEG) + (size_t)ns * SEG;

#pragma unroll 1
  for (int ch = 0; ch < nchunk; ++ch) {
    const int cbase = col0 + ch * BN;
    f32x4 acc[2][4];
#pragma unroll
    for (int i = 0; i < 2; ++i)
#pragma unroll
      for (int j = 0; j < 4; ++j) acc[i][j] = (f32x4){0.f, 0.f, 0.f, 0.f};

    K_PIPELINE4()
    // WAITB(0) drained; barrier passed -> tiles/bsq_s readable.

    // ---- filter epilogue: dist < tau0 -> LDS-counted private segment ----
#pragma unroll
    for (int fn = 0; fn < 4; ++fn) {
      const int c = cbase + wn * 64 + fn * 16 + fr;
      const bool cv = (c < col1);
      const float bq = bsq_s[ch & 1][wn * 64 + fn * 16 + fr];
#pragma unroll
      for (int fm = 0; fm < 2; ++fm) {
#pragma unroll
        for (int j = 0; j < 4; ++j) {
          const int rl = wm * 32 + fm * 16 + rj + j;
          const float dist = xsq_s[rl] + bq - 2.0f * acc[fm][fn][j];
          if (cv && dist < tau_s[rl]) {
            int ix = atomicAdd(&svcnt[rl], 1);       // LDS atomic (rare: ~3%)
            if (ix < SEG)
              seg_base[(size_t)rl * (NSPLIT_B * SEG) + ix] = dist;
          }
        }
      }
    }
    DRAIN_VM();                       // retire stores: keeps vmcnt ledger clean
    if (ch + 1 < nchunk) {            // next-chunk prologue (WAR-safe: all
      STAGE_BSQ(ch + 1);              // waves passed t=13/14/15 barriers)
      int gcn = cbase + BN + stg_row;
      if (gcn > VOCAB - 1) gcn = VOCAB - 1;
      b_src = bh + (size_t)gcn * DMODEL + stg_gran;
      STAGE_STEP(0, 0);
      STAGE_STEP(TSZ, BK);
      STAGE_STEP(2 * TSZ, 2 * BK);
    }
  }

  LBAR();                             // all LDS atomics visible
  if (tid < BM) {
    int c = svcnt[tid]; if (c > SEG) c = SEG;
    gcnt[(size_t)(mrow0 + tid) * NSPLIT_B + ns] = c;
  }
}

// ---------------------------------------------------------------------------
// Kernel 5 (pass C): per row, top-64 = sample64 merged with all survivors
// from the 16 per-block segments. One wave per row.
// ---------------------------------------------------------------------------
__global__ __launch_bounds__(256) void select_kernel(
    const float* __restrict__ gcand, const int* __restrict__ gcnt,
    const float* __restrict__ sample64, float* __restrict__ out) {
  const int lane = threadIdx.x & 63;
  const int row = blockIdx.x * 4 + (threadIdx.x >> 6);
  float lst = sample64[(size_t)row * KSEL + lane];   // sorted asc
#pragma unroll 1
  for (int s = 0; s < NSPLIT_B; ++s) {
    int cnt = gcnt[(size_t)row * NSPLIT_B + s];
    const float* src = gcand + (size_t)row * (NSPLIT_B * SEG) + (size_t)s * SEG;
#pragma unroll 1
    for (int base = 0; base < cnt; base += 64) {
      int n = cnt - base; if (n > 64) n = 64;
      lst = merge_row(lst, src + base, n);
    }
  }
  out[(size_t)row * KSEL + lane] = lst;
}

// ---------------------------------------------------------------------------
extern "C" void kernel_launch(void* const* d_in, const int* in_sizes, int n_in,
                              void* d_out, int out_size, void* d_ws, size_t ws_size,
                              hipStream_t stream) {
  const float* x = (const float*)d_in[0];
  const float* b = (const float*)d_in[1];
  // d_in[2] = target (unused), d_in[3] = k (hardcoded 64)
  float* out = (float*)d_out;
  char* ws = (char*)d_ws;

  size_t off = 0;
  uint8_t* xh = (uint8_t*)(ws + off); off += (size_t)TOKENS * DMODEL;          // 4.2 MB
  uint8_t* bh = (uint8_t*)(ws + off); off += (size_t)VOCAB * DMODEL;           // 51.5 MB
  off = (off + 255) & ~(size_t)255;
  float* xsq = (float*)(ws + off); off += (size_t)TOKENS * sizeof(float);
  float* bsq = (float*)(ws + off); off += (((size_t)VOCAB * sizeof(float)) + 255) & ~(size_t)255;
  float* sample64 = (float*)(ws + off); off += (size_t)TOKENS * KSEL * sizeof(float);         // 1 MB
  int* gcnt = (int*)(ws + off); off += (size_t)TOKENS * NSPLIT_B * sizeof(int);               // 256 KB
  float* sdist = (float*)(ws + off); off += (size_t)TOKENS * SAMPLE_END * sizeof(float);      // 33.5 MB
  float* gcand = (float*)(ws + off); off += (size_t)TOKENS * NSPLIT_B * SEG * sizeof(float);  // 67 MB

  prep_kernel<<<TOKENS + VOCAB, 256, 0, stream>>>(x, b, xh, bh, xsq, bsq);
  gemm_sample_dist<<<(TOKENS / BM) * NSPLIT_A, 512, 0, stream>>>(xh, bh, xsq, bsq, sdist);
  sample_reduce_kernel<<<TOKENS / 4, 256, 0, stream>>>(sdist, sample64);
  gemm_filter_kernel<<<(TOKENS / BM) * NSPLIT_B, 512, 0, stream>>>(xh, bh, xsq, bsq, sample64, gcand, gcnt);
  select_kernel<<<TOKENS / 4, 256, 0, stream>>>(gcand, gcnt, sample64, out);
}